// Round 1
// baseline (5232.161 us; speedup 1.0000x reference)
//
#include <hip/hip_runtime.h>
#include <hip/hip_bf16.h>
#include <math.h>

#define SEQ 2048
#define CDIM 1536
#define HN 8
#define DKC 64
#define DVC 192
#define BN 2
#define NPOS 4095   // 2*SEQ-1
#define HDK 512     // H*DK
#define HDV 1536    // H*DV

// ---------------- positional features (raw) + per-basis gamma max ----------------
__global__ void pos_feat_kernel(float* __restrict__ pe_raw, unsigned* __restrict__ gmax) {
  int item = blockIdx.x * 256 + threadIdx.x;
  if (item >= 32 * NPOS) return;
  int j = item / NPOS;
  int pos = item - j * NPOS;
  float p = (float)(pos - (SEQ - 1));
  float ap = fabsf(p);
  // exponential decay: exp(-ln2/half_life * ap) = 2^(-ap/half_life)
  float hl = exp2f(3.0f + 8.0f * (float)j / 31.0f);
  float fe = exp2f(-ap / hl);
  // central mask
  float cw = exp2f((float)(j + 1)) - 1.0f;
  float fc = (cw > ap) ? 1.0f : 0.0f;
  // gamma pdf (linspace(64,2048,32) == 64*(j+1) exactly)
  float conc = 4.0f * (float)((j + 1) * (j + 1));
  float rate = (float)(j + 1) / 16.0f;
  float log_norm = lgammaf(conc) - conc * logf(rate);
  float log_un = (conc - 1.0f) * logf(ap) - rate * ap;  // ap=0 -> -inf -> prob 0
  float prob = expf(log_un - log_norm) + 1e-8f;
  pe_raw[j * NPOS + pos] = fe;
  pe_raw[(32 + j) * NPOS + pos] = fc;
  pe_raw[(64 + j) * NPOS + pos] = prob;
  atomicMax(&gmax[j], __float_as_uint(prob));  // prob>0: uint bits order-preserving
}

// ---------------- r_kT[h*64+d][pos] = sum_f pe[pos,f] * Wr[f, h*64+d] ----------------
// fuses gamma max-normalization and the sign-concat: pe[:,96+f] = sgn*pe[:,f]
__global__ __launch_bounds__(256) void rk_kernel(const float* __restrict__ pe_raw,
                                                 const unsigned* __restrict__ gmax,
                                                 const float* __restrict__ Wr,
                                                 float* __restrict__ r_kT) {
  int col = blockIdx.y;  // 0..511
  int tid = threadIdx.x;
  __shared__ float w0s[96], w1s[96], ginv[32];
  for (int f = tid; f < 96; f += 256) {
    w0s[f] = Wr[f * HDK + col];
    w1s[f] = Wr[(96 + f) * HDK + col];
  }
  if (tid < 32) ginv[tid] = 1.0f / __uint_as_float(gmax[tid]);
  __syncthreads();
  int pos = blockIdx.x * 256 + tid;
  if (pos >= NPOS) return;
  float sgn = (pos > SEQ - 1) ? 1.0f : ((pos < SEQ - 1) ? -1.0f : 0.0f);
  float acc = 0.0f;
#pragma unroll 8
  for (int f = 0; f < 64; f++) {
    float val = pe_raw[f * NPOS + pos];
    acc = fmaf(val, fmaf(sgn, w1s[f], w0s[f]), acc);
  }
#pragma unroll 8
  for (int f = 64; f < 96; f++) {
    float val = pe_raw[f * NPOS + pos] * ginv[f - 64];
    acc = fmaf(val, fmaf(sgn, w1s[f], w0s[f]), acc);
  }
  r_kT[(size_t)col * NPOS + pos] = acc;
}

// ---------------- tiled fp32 GEMM: out = A[M,K] @ W[K,N], various store layouts ----
// MODE 0: q    -> out[r*N+c] * DK^-0.5              (natural [4096,512])
// MODE 1: kT   -> out[((b*8+h)*64+d)*SEQ + j]       (transposed [B,H,DK,S])
// MODE 2: v    -> out[((b*8+h)*SEQ + j)*DV + e]     ([B,H,S,DV])
// MODE 3: out  -> out[r*N+c] + bias[c]              (final projection)
template <int MODE>
__global__ __launch_bounds__(256) void gemm_kernel(const float* __restrict__ A,
                                                   const float* __restrict__ W,
                                                   const float* __restrict__ bias,
                                                   float* __restrict__ out,
                                                   int M, int N, int K) {
  __shared__ float As[16][68];  // [k][row], pad keeps float4 alignment
  __shared__ float Bs[16][64];  // [k][col]
  int tid = threadIdx.x;
  int tx = tid & 15, ty = tid >> 4;
  int row0 = blockIdx.y * 64, col0 = blockIdx.x * 64;
  int lr = tid >> 2;            // A: row within tile
  int lk4 = (tid & 3) << 2;     // A: k offset (float4)
  int wk = tid >> 4;            // W: k within tile
  int wc4 = (tid & 15) << 2;    // W: col offset (float4)
  float acc[4][4] = {};
  const float* Aptr = A + (size_t)(row0 + lr) * K + lk4;
  const float* Wptr = W + (size_t)wk * N + col0 + wc4;
  for (int k0 = 0; k0 < K; k0 += 16) {
    float4 a4 = *(const float4*)(Aptr + k0);
    float4 b4 = *(const float4*)(Wptr + (size_t)k0 * N);
    As[lk4 + 0][lr] = a4.x;
    As[lk4 + 1][lr] = a4.y;
    As[lk4 + 2][lr] = a4.z;
    As[lk4 + 3][lr] = a4.w;
    *(float4*)&Bs[wk][wc4] = b4;
    __syncthreads();
#pragma unroll
    for (int kk = 0; kk < 16; kk++) {
      float4 av = *(const float4*)&As[kk][ty << 2];
      float4 bv = *(const float4*)&Bs[kk][tx << 2];
      float a[4] = {av.x, av.y, av.z, av.w};
      float b[4] = {bv.x, bv.y, bv.z, bv.w};
#pragma unroll
      for (int i2 = 0; i2 < 4; i2++)
#pragma unroll
        for (int j2 = 0; j2 < 4; j2++)
          acc[i2][j2] = fmaf(a[i2], b[j2], acc[i2][j2]);
    }
    __syncthreads();
  }
#pragma unroll
  for (int i2 = 0; i2 < 4; i2++) {
    int r = row0 + (ty << 2) + i2;
    int bb = r >> 11, jj = r & (SEQ - 1);
#pragma unroll
    for (int j2 = 0; j2 < 4; j2++) {
      int c = col0 + (tx << 2) + j2;
      float vv = acc[i2][j2];
      if (MODE == 0) {
        out[(size_t)r * N + c] = vv * 0.125f;
      } else if (MODE == 1) {
        int h = c >> 6, d = c & 63;
        out[(((size_t)bb * HN + h) * DKC + d) * SEQ + jj] = vv;
      } else if (MODE == 2) {
        int h = c / DVC, e = c % DVC;
        out[(((size_t)bb * HN + h) * SEQ + jj) * DVC + e] = vv;
      } else {
        out[(size_t)r * N + c] = vv + bias[c];
      }
    }
  }
}

// ---------------- fused attention: one workgroup per (b,h,query row) ----------------
// logits[i,j] = q_i . k_j  +  (q_i + rwb_h) . r_k[h, j-i+SEQ-1]   (relative_shift inlined)
__global__ __launch_bounds__(256) void attn_kernel(const float* __restrict__ q,
                                                   const float* __restrict__ kT,
                                                   const float* __restrict__ v,
                                                   const float* __restrict__ r_kT,
                                                   const float* __restrict__ rwb,
                                                   const int* __restrict__ mask,
                                                   float* __restrict__ attn) {
  int i = blockIdx.x;
  int bh = blockIdx.y;
  int b = bh >> 3, h = bh & 7;
  int tid = threadIdx.x;
  __shared__ float ls[SEQ];
  __shared__ float qs[64], qbs[64];
  __shared__ float red[8];
  if (tid < 64) {
    float qv = q[((size_t)(b * SEQ + i)) * HDK + h * 64 + tid];
    qs[tid] = qv;
    qbs[tid] = qv + rwb[h * 64 + tid];
  }
  __syncthreads();
  const float* kbase = kT + (size_t)bh * 64 * SEQ;
  const float* rbase = r_kT + (size_t)h * 64 * NPOS;
  const int* mrow = mask + b * SEQ;
  for (int j = tid; j < SEQ; j += 256) {
    float acc = 0.f, racc = 0.f;
    const float* kp = kbase + j;
    const float* rp = rbase + (j - i + SEQ - 1);
#pragma unroll 8
    for (int d = 0; d < 64; d++) {
      acc = fmaf(qs[d], kp[d * SEQ], acc);
      racc = fmaf(qbs[d], rp[d * NPOS], racc);
    }
    float l = acc + racc;
    ls[j] = (mrow[j] == 0) ? -1e9f : l;
  }
  __syncthreads();
  // row max
  float m = -INFINITY;
  for (int j = tid; j < SEQ; j += 256) m = fmaxf(m, ls[j]);
#pragma unroll
  for (int off = 32; off > 0; off >>= 1) m = fmaxf(m, __shfl_down(m, off));
  if ((tid & 63) == 0) red[tid >> 6] = m;
  __syncthreads();
  m = fmaxf(fmaxf(red[0], red[1]), fmaxf(red[2], red[3]));
  // exp + sum (keep unnormalized weights in LDS; scale output at the end)
  float ssum = 0.f;
  for (int j = tid; j < SEQ; j += 256) {
    float w = __expf(ls[j] - m);
    ls[j] = w;
    ssum += w;
  }
#pragma unroll
  for (int off = 32; off > 0; off >>= 1) ssum += __shfl_down(ssum, off);
  if ((tid & 63) == 0) red[4 + (tid >> 6)] = ssum;
  __syncthreads();
  float inv = 1.0f / (red[4] + red[5] + red[6] + red[7]);
  // weights @ v
  if (tid < DVC) {
    const float* vp = v + ((size_t)bh * SEQ) * DVC + tid;
    float acc = 0.f;
#pragma unroll 8
    for (int j = 0; j < SEQ; j++) acc = fmaf(ls[j], vp[(size_t)j * DVC], acc);
    attn[((size_t)(b * SEQ + i)) * HDV + h * DVC + tid] = acc * inv;
  }
}

extern "C" void kernel_launch(void* const* d_in, const int* in_sizes, int n_in,
                              void* d_out, int out_size, void* d_ws, size_t ws_size,
                              hipStream_t stream) {
  const float* x    = (const float*)d_in[0];
  const int*   mask = (const int*)d_in[1];
  const float* Wq   = (const float*)d_in[2];
  const float* Wk   = (const float*)d_in[3];
  const float* Wv   = (const float*)d_in[4];
  const float* Wr   = (const float*)d_in[5];
  const float* rwb  = (const float*)d_in[6];
  const float* Wo   = (const float*)d_in[7];
  const float* bo   = (const float*)d_in[8];
  float* out = (float*)d_out;

  float* ws = (float*)d_ws;
  size_t off = 0;
  float* q      = ws + off; off += (size_t)BN * SEQ * HDK;   // 2,097,152
  float* kT     = ws + off; off += (size_t)BN * SEQ * HDK;   // 2,097,152
  float* v      = ws + off; off += (size_t)BN * SEQ * HDV;   // 6,291,456
  float* r_kT   = ws + off; off += (size_t)HDK * NPOS;       // 2,096,640
  float* pe_raw = ws + off; off += (size_t)96 * NPOS;        //   393,120
  unsigned* gmax = (unsigned*)(ws + off); off += 32;
  float* attn   = ws + off; off += (size_t)BN * SEQ * HDV;   // 6,291,456
  // total ~77 MB of workspace

  hipMemsetAsync(gmax, 0, 32 * sizeof(unsigned), stream);
  pos_feat_kernel<<<(32 * NPOS + 255) / 256, 256, 0, stream>>>(pe_raw, gmax);
  rk_kernel<<<dim3(16, HDK), 256, 0, stream>>>(pe_raw, gmax, Wr, r_kT);
  gemm_kernel<0><<<dim3(HDK / 64, (BN * SEQ) / 64), 256, 0, stream>>>(x, Wq, nullptr, q,  BN * SEQ, HDK, CDIM);
  gemm_kernel<1><<<dim3(HDK / 64, (BN * SEQ) / 64), 256, 0, stream>>>(x, Wk, nullptr, kT, BN * SEQ, HDK, CDIM);
  gemm_kernel<2><<<dim3(HDV / 64, (BN * SEQ) / 64), 256, 0, stream>>>(x, Wv, nullptr, v,  BN * SEQ, HDV, CDIM);
  attn_kernel<<<dim3(SEQ, BN * HN), 256, 0, stream>>>(q, kT, v, r_kT, rwb, mask, attn);
  gemm_kernel<3><<<dim3(HDV / 64, (BN * SEQ) / 64), 256, 0, stream>>>(attn, Wo, bo, out, BN * SEQ, HDV, CDIM);
}

// Round 2
// 2118.815 us; speedup vs baseline: 2.4694x; 2.4694x over previous
//
#include <hip/hip_runtime.h>
#include <math.h>

#define SEQ 2048
#define CDIM 1536
#define HN 8
#define DKC 64
#define DVC 192
#define BN 2
#define NPOS 4095   // 2*SEQ-1
#define HDK 512     // H*DK
#define HDV 1536    // H*DV
#define LSTR 72     // LDS bf16 row stride (64 data + 8 pad; keeps 16B alignment, 2-way banks)
#define RSTR 84     // LDS fp32 row stride for R scratch

typedef __attribute__((ext_vector_type(8))) short bf8v;   // 8 bf16 (4 VGPRs)
typedef __attribute__((ext_vector_type(4))) float f4v;    // MFMA C/D frag
typedef unsigned short ushort_t;

static __device__ __forceinline__ float bf2f(ushort_t h) {
  union { unsigned int u; float f; } c; c.u = ((unsigned int)h) << 16; return c.f;
}
static __device__ __forceinline__ ushort_t f2bf(float f) {
  union { float f; unsigned int u; } c; c.f = f;
  return (ushort_t)((c.u + 0x7fffu + ((c.u >> 16) & 1u)) >> 16);
}

// ---------------- positional features (raw) + per-basis gamma max ----------------
__global__ void pos_feat_kernel(float* __restrict__ pe_raw, unsigned* __restrict__ gmax) {
  int item = blockIdx.x * 256 + threadIdx.x;
  if (item >= 32 * NPOS) return;
  int j = item / NPOS;
  int pos = item - j * NPOS;
  float p = (float)(pos - (SEQ - 1));
  float ap = fabsf(p);
  float hl = exp2f(3.0f + 8.0f * (float)j / 31.0f);
  float fe = exp2f(-ap / hl);
  float cw = exp2f((float)(j + 1)) - 1.0f;
  float fc = (cw > ap) ? 1.0f : 0.0f;
  float conc = 4.0f * (float)((j + 1) * (j + 1));
  float rate = (float)(j + 1) / 16.0f;
  float log_norm = lgammaf(conc) - conc * logf(rate);
  float log_un = (conc - 1.0f) * logf(ap) - rate * ap;
  float prob = expf(log_un - log_norm) + 1e-8f;
  pe_raw[j * NPOS + pos] = fe;
  pe_raw[(32 + j) * NPOS + pos] = fc;
  pe_raw[(64 + j) * NPOS + pos] = prob;
  atomicMax(&gmax[j], __float_as_uint(prob));
}

// ------------- r_k (bf16, [H][4096][64] t-major) = pe @ Wr, sign-concat fused -------------
__global__ __launch_bounds__(256) void rk_kernel(const float* __restrict__ pe_raw,
                                                 const unsigned* __restrict__ gmax,
                                                 const float* __restrict__ Wr,
                                                 ushort_t* __restrict__ rkb) {
  int col = blockIdx.y;  // 0..511 = h*64+d
  int tid = threadIdx.x;
  __shared__ float w0s[96], w1s[96], ginv[32];
  for (int f = tid; f < 96; f += 256) {
    w0s[f] = Wr[f * HDK + col];
    w1s[f] = Wr[(96 + f) * HDK + col];
  }
  if (tid < 32) ginv[tid] = 1.0f / __uint_as_float(gmax[tid]);
  __syncthreads();
  int pos = blockIdx.x * 256 + tid;
  if (pos >= NPOS) return;
  float sgn = (pos > SEQ - 1) ? 1.0f : ((pos < SEQ - 1) ? -1.0f : 0.0f);
  float acc = 0.0f;
#pragma unroll 8
  for (int f = 0; f < 64; f++) {
    float val = pe_raw[f * NPOS + pos];
    acc = fmaf(val, fmaf(sgn, w1s[f], w0s[f]), acc);
  }
#pragma unroll 8
  for (int f = 64; f < 96; f++) {
    float val = pe_raw[f * NPOS + pos] * ginv[f - 64];
    acc = fmaf(val, fmaf(sgn, w1s[f], w0s[f]), acc);
  }
  rkb[((size_t)(col >> 6) * 4096 + pos) * 64 + (col & 63)] = f2bf(acc);
}

// ---------------- tiled fp32 GEMM with layout/dtype-specialized stores ----
// MODE 0: q bf16 [B*S,512] scaled by 0.125
// MODE 1: k bf16 [B,H,S,64]
// MODE 2: vT bf16 [B,H,192,S]
// MODE 3: fp32 out + bias (final projection)
template <int MODE>
__global__ __launch_bounds__(256) void gemm_kernel(const float* __restrict__ A,
                                                   const float* __restrict__ W,
                                                   const float* __restrict__ bias,
                                                   void* __restrict__ outv,
                                                   int M, int N, int K) {
  __shared__ float As[16][68];
  __shared__ float Bs[16][64];
  int tid = threadIdx.x;
  int tx = tid & 15, ty = tid >> 4;
  int row0 = blockIdx.y * 64, col0 = blockIdx.x * 64;
  int lr = tid >> 2;
  int lk4 = (tid & 3) << 2;
  int wk = tid >> 4;
  int wc4 = (tid & 15) << 2;
  float acc[4][4] = {};
  const float* Aptr = A + (size_t)(row0 + lr) * K + lk4;
  const float* Wptr = W + (size_t)wk * N + col0 + wc4;
  for (int k0 = 0; k0 < K; k0 += 16) {
    float4 a4 = *(const float4*)(Aptr + k0);
    float4 b4 = *(const float4*)(Wptr + (size_t)k0 * N);
    As[lk4 + 0][lr] = a4.x;
    As[lk4 + 1][lr] = a4.y;
    As[lk4 + 2][lr] = a4.z;
    As[lk4 + 3][lr] = a4.w;
    *(float4*)&Bs[wk][wc4] = b4;
    __syncthreads();
#pragma unroll
    for (int kk = 0; kk < 16; kk++) {
      float4 av = *(const float4*)&As[kk][ty << 2];
      float4 bv = *(const float4*)&Bs[kk][tx << 2];
      float a[4] = {av.x, av.y, av.z, av.w};
      float b[4] = {bv.x, bv.y, bv.z, bv.w};
#pragma unroll
      for (int i2 = 0; i2 < 4; i2++)
#pragma unroll
        for (int j2 = 0; j2 < 4; j2++)
          acc[i2][j2] = fmaf(a[i2], b[j2], acc[i2][j2]);
    }
    __syncthreads();
  }
#pragma unroll
  for (int i2 = 0; i2 < 4; i2++) {
    int r = row0 + (ty << 2) + i2;
    int bb = r >> 11, jj = r & (SEQ - 1);
#pragma unroll
    for (int j2 = 0; j2 < 4; j2++) {
      int c = col0 + (tx << 2) + j2;
      float vv = acc[i2][j2];
      if (MODE == 0) {
        ((ushort_t*)outv)[(size_t)r * HDK + c] = f2bf(vv * 0.125f);
      } else if (MODE == 1) {
        int h = c >> 6, d = c & 63;
        ((ushort_t*)outv)[(((size_t)bb * HN + h) * SEQ + jj) * 64 + d] = f2bf(vv);
      } else if (MODE == 2) {
        int h = c / DVC, e = c - h * DVC;
        ((ushort_t*)outv)[(((size_t)bb * HN + h) * DVC + e) * SEQ + jj] = f2bf(vv);
      } else {
        ((float*)outv)[(size_t)r * N + c] = vv + bias[c];
      }
    }
  }
}

// ---------------- flash-style MFMA attention ----------------
// grid (S/64, B*H); 4 waves; wave w owns query rows [i0+16w, i0+16w+16)
// logits[i,j] = q_i.k_j + (q_i+rwb).r_k[j-i+2047]  (relative_shift inlined as band)
__global__ __launch_bounds__(256, 2) void attn_mfma(
    const ushort_t* __restrict__ qb,   // [B*S, 512] bf16, pre-scaled
    const ushort_t* __restrict__ kb,   // [B,H,S,64] bf16
    const ushort_t* __restrict__ vtb,  // [B,H,192,S] bf16
    const ushort_t* __restrict__ rkb,  // [H,4096,64] bf16
    const float* __restrict__ rwb,     // [512]
    const int* __restrict__ mask,      // [B,S]
    float* __restrict__ attn)          // [B*S, 1536] fp32
{
  // UNI holds RK[128][LSTR] (18432B) + Kt[64][LSTR] (9216B); R fp32 scratch
  // (4*16*RSTR*4 = 21504B) aliases it after both are consumed each tile.
  __shared__ __align__(16) char UNI[27648];
  __shared__ ushort_t Vts[192 * LSTR];
  __shared__ ushort_t Pbs[4 * 16 * LSTR];
  __shared__ float mb[64];
  ushort_t* RKs = (ushort_t*)UNI;
  ushort_t* Kts = (ushort_t*)(UNI + 18432);
  float* Rs = (float*)UNI;

  const int i0 = blockIdx.x * 64;
  const int bh = blockIdx.y, b = bh >> 3, h = bh & 7;
  const int tid = threadIdx.x;
  const int wv = tid >> 6, lane = tid & 63;
  const int l15 = lane & 15, quad = lane >> 4;

  // Q strip A-fragments (held in VGPRs across all key tiles)
  bf8v qf[2], qbf[2];
  {
    int qrow = i0 + wv * 16 + l15;
    const ushort_t* qp = qb + (size_t)(b * SEQ + qrow) * HDK + h * 64;
#pragma unroll
    for (int kc = 0; kc < 2; kc++) {
      bf8v qv = *(const bf8v*)(qp + kc * 32 + quad * 8);
      qf[kc] = qv;
      bf8v t;
#pragma unroll
      for (int j = 0; j < 8; j++) {
        float f = bf2f((ushort_t)qv[j]) + rwb[h * 64 + kc * 32 + quad * 8 + j];
        t[j] = (short)f2bf(f);
      }
      qbf[kc] = t;
    }
  }

  f4v Of[12];
#pragma unroll
  for (int se = 0; se < 12; se++) Of[se] = (f4v)0.0f;
  float m_i[4] = {-INFINITY, -INFINITY, -INFINITY, -INFINITY};
  float l_i[4] = {0.f, 0.f, 0.f, 0.f};

  for (int j0 = 0; j0 < SEQ; j0 += 64) {
    __syncthreads();  // prev-tile readers done before staging overwrites
    {
      const int U0 = j0 - i0 + 1984;  // in [0, 3968]
#pragma unroll
      for (int r = 0; r < 2; r++) {
        int idx = tid + r * 256, row = idx >> 3, seg = idx & 7;
        *(bf8v*)(Kts + row * LSTR + seg * 8) =
            *(const bf8v*)(kb + ((size_t)bh * SEQ + j0 + row) * 64 + seg * 8);
      }
#pragma unroll
      for (int r = 0; r < 6; r++) {
        int idx = tid + r * 256, row = idx >> 3, seg = idx & 7;
        *(bf8v*)(Vts + row * LSTR + seg * 8) =
            *(const bf8v*)(vtb + ((size_t)bh * DVC + row) * SEQ + j0 + seg * 8);
      }
#pragma unroll
      for (int r = 0; r < 4; r++) {
        int idx = tid + r * 256, row = idx >> 3, seg = idx & 7;
        *(bf8v*)(RKs + row * LSTR + seg * 8) =
            *(const bf8v*)(rkb + ((size_t)h * 4096 + U0 + row) * 64 + seg * 8);
      }
      if (tid < 64) mb[tid] = mask[b * SEQ + j0 + tid] ? 0.f : -1.0f;
    }
    __syncthreads();

    // content logits: S[16,64] per wave = Q_strip @ K_tile^T
    f4v Sf[4];
#pragma unroll
    for (int s = 0; s < 4; s++) {
      Sf[s] = (f4v)0.0f;
#pragma unroll
      for (int kc = 0; kc < 2; kc++) {
        bf8v kf = *(const bf8v*)(Kts + (s * 16 + l15) * LSTR + kc * 32 + quad * 8);
        Sf[s] = __builtin_amdgcn_mfma_f32_16x16x32_bf16(qf[kc], kf, Sf[s], 0, 0, 0);
      }
    }
    // rel logits: R[16,80] per wave = QB_strip @ RK_window^T
    f4v Rf[5];
    const int tb = 48 - 16 * wv;  // 16-aligned window start in shared RK
#pragma unroll
    for (int u = 0; u < 5; u++) {
      Rf[u] = (f4v)0.0f;
#pragma unroll
      for (int kc = 0; kc < 2; kc++) {
        bf8v rf = *(const bf8v*)(RKs + (tb + u * 16 + l15) * LSTR + kc * 32 + quad * 8);
        Rf[u] = __builtin_amdgcn_mfma_f32_16x16x32_bf16(qbf[kc], rf, Rf[u], 0, 0, 0);
      }
    }
    __syncthreads();  // all waves done reading RK/Kt; R may now alias them
    float* Rw = Rs + wv * 16 * RSTR;
#pragma unroll
    for (int u = 0; u < 5; u++)
#pragma unroll
      for (int reg = 0; reg < 4; reg++)
        Rw[(quad * 4 + reg) * RSTR + u * 16 + l15] = Rf[u][reg];

    // band extraction (t_local = c - r + 15) + mask, intra-wave (DS is in-order per wave)
#pragma unroll
    for (int s = 0; s < 4; s++)
#pragma unroll
      for (int reg = 0; reg < 4; reg++) {
        int r = quad * 4 + reg;
        int c = s * 16 + l15;
        float li = Sf[s][reg] + Rw[r * RSTR + (c - r + 15)];
        Sf[s][reg] = (mb[c] == 0.f) ? li : -1e9f;
      }

    // online softmax per row (row r = quad*4+reg lives in 16 lanes of the quad)
#pragma unroll
    for (int reg = 0; reg < 4; reg++) {
      float t = fmaxf(fmaxf(Sf[0][reg], Sf[1][reg]), fmaxf(Sf[2][reg], Sf[3][reg]));
      t = fmaxf(t, __shfl_xor(t, 1));
      t = fmaxf(t, __shfl_xor(t, 2));
      t = fmaxf(t, __shfl_xor(t, 4));
      t = fmaxf(t, __shfl_xor(t, 8));
      float mn = fmaxf(m_i[reg], t);
      float alpha = __expf(m_i[reg] - mn);
      m_i[reg] = mn;
      l_i[reg] *= alpha;
#pragma unroll
      for (int se = 0; se < 12; se++) Of[se][reg] *= alpha;
      float rs = 0.f;
#pragma unroll
      for (int s = 0; s < 4; s++) {
        float p = __expf(Sf[s][reg] - mn);
        Sf[s][reg] = p;
        rs += p;
      }
      rs += __shfl_xor(rs, 1);
      rs += __shfl_xor(rs, 2);
      rs += __shfl_xor(rs, 4);
      rs += __shfl_xor(rs, 8);
      l_i[reg] += rs;
#pragma unroll
      for (int s = 0; s < 4; s++)
        Pbs[(wv * 16 + quad * 4 + reg) * LSTR + s * 16 + l15] = f2bf(Sf[s][reg]);
    }

    // PV: O[16,192] += P[16,64] @ V_tile (V staged transposed)
    bf8v pa[2];
#pragma unroll
    for (int kc = 0; kc < 2; kc++)
      pa[kc] = *(const bf8v*)(Pbs + (wv * 16 + l15) * LSTR + kc * 32 + quad * 8);
#pragma unroll
    for (int se = 0; se < 12; se++) {
#pragma unroll
      for (int kc = 0; kc < 2; kc++) {
        bf8v vf = *(const bf8v*)(Vts + (se * 16 + l15) * LSTR + kc * 32 + quad * 8);
        Of[se] = __builtin_amdgcn_mfma_f32_16x16x32_bf16(pa[kc], vf, Of[se], 0, 0, 0);
      }
    }
  }

#pragma unroll
  for (int reg = 0; reg < 4; reg++) {
    float inv = 1.0f / l_i[reg];
    int row = i0 + wv * 16 + quad * 4 + reg;
    float* op = attn + (size_t)(b * SEQ + row) * HDV + h * DVC;
#pragma unroll
    for (int se = 0; se < 12; se++)
      op[se * 16 + l15] = Of[se][reg] * inv;
  }
}

extern "C" void kernel_launch(void* const* d_in, const int* in_sizes, int n_in,
                              void* d_out, int out_size, void* d_ws, size_t ws_size,
                              hipStream_t stream) {
  const float* x    = (const float*)d_in[0];
  const int*   mask = (const int*)d_in[1];
  const float* Wq   = (const float*)d_in[2];
  const float* Wk   = (const float*)d_in[3];
  const float* Wv   = (const float*)d_in[4];
  const float* Wr   = (const float*)d_in[5];
  const float* rwb  = (const float*)d_in[6];
  const float* Wo   = (const float*)d_in[7];
  const float* bo   = (const float*)d_in[8];
  float* out = (float*)d_out;

  float* ws = (float*)d_ws;
  size_t off = 0;
  float* attnb  = ws + off; off += (size_t)BN * SEQ * HDV;       // 6,291,456 f32
  float* pe_raw = ws + off; off += (size_t)96 * NPOS;            //   393,120 f32
  unsigned* gmax = (unsigned*)(ws + off); off += 32;
  ushort_t* qb  = (ushort_t*)(ws + off); off += (size_t)BN * SEQ * HDK / 2;        // bf16
  ushort_t* kb  = (ushort_t*)(ws + off); off += (size_t)BN * SEQ * HDK / 2;        // bf16
  ushort_t* vtb = (ushort_t*)(ws + off); off += (size_t)BN * SEQ * HDV / 2;        // bf16
  ushort_t* rkb = (ushort_t*)(ws + off); off += (size_t)HN * 4096 * 64 / 2;        // bf16

  hipMemsetAsync(gmax, 0, 32 * sizeof(unsigned), stream);
  pos_feat_kernel<<<(32 * NPOS + 255) / 256, 256, 0, stream>>>(pe_raw, gmax);
  rk_kernel<<<dim3(16, HDK), 256, 0, stream>>>(pe_raw, gmax, Wr, rkb);
  gemm_kernel<0><<<dim3(HDK / 64, (BN * SEQ) / 64), 256, 0, stream>>>(x, Wq, nullptr, qb,  BN * SEQ, HDK, CDIM);
  gemm_kernel<1><<<dim3(HDK / 64, (BN * SEQ) / 64), 256, 0, stream>>>(x, Wk, nullptr, kb,  BN * SEQ, HDK, CDIM);
  gemm_kernel<2><<<dim3(HDV / 64, (BN * SEQ) / 64), 256, 0, stream>>>(x, Wv, nullptr, vtb, BN * SEQ, HDV, CDIM);
  attn_mfma<<<dim3(SEQ / 64, BN * HN), 256, 0, stream>>>(qb, kb, vtb, rkb, rwb, mask, attnb);
  gemm_kernel<3><<<dim3(HDV / 64, (BN * SEQ) / 64), 256, 0, stream>>>(attnb, Wo, bo, out, BN * SEQ, HDV, CDIM);
}

// Round 3
// 466.737 us; speedup vs baseline: 11.2101x; 4.5396x over previous
//
#include <hip/hip_runtime.h>
#include <math.h>

#define SEQ 2048
#define CDIM 1536
#define HN 8
#define DKC 64
#define DVC 192
#define BN 2
#define NPOS 4095   // 2*SEQ-1
#define HDK 512     // H*DK
#define HDV 1536    // H*DV
#define LSTR 72     // LDS bf16 row stride in attn (64 data + 8 pad)
#define RSTR 84     // LDS fp32 row stride for R scratch in attn

typedef __attribute__((ext_vector_type(8))) short bf8v;   // 8 bf16 (4 VGPRs)
typedef __attribute__((ext_vector_type(4))) float f4v;    // MFMA C/D frag
typedef unsigned short ushort_t;

static __device__ __forceinline__ float bf2f(ushort_t h) {
  union { unsigned int u; float f; } c; c.u = ((unsigned int)h) << 16; return c.f;
}
static __device__ __forceinline__ ushort_t f2bf(float f) {
  union { float f; unsigned int u; } c; c.f = f;
  return (ushort_t)((c.u + 0x7fffu + ((c.u >> 16) & 1u)) >> 16);
}
static __device__ __forceinline__ void gl2lds16(const void* g, void* l) {
  __builtin_amdgcn_global_load_lds((const __attribute__((address_space(1))) unsigned int*)g,
                                   (__attribute__((address_space(3))) unsigned int*)l,
                                   16, 0, 0);
}

// ---------------- positional features + per-basis gamma max (block-reduced atomics) ---------
// grid (16, 32): blockIdx.y = basis j, blockIdx.x*256+tid = pos
__global__ __launch_bounds__(256) void pos_feat_kernel(float* __restrict__ pe_raw,
                                                       unsigned* __restrict__ gmax) {
  int j = blockIdx.y;
  int pos = blockIdx.x * 256 + threadIdx.x;
  float prob = 0.0f;
  if (pos < NPOS) {
    float p = (float)(pos - (SEQ - 1));
    float ap = fabsf(p);
    float hl = exp2f(3.0f + 8.0f * (float)j / 31.0f);
    float fe = exp2f(-ap / hl);
    float cw = exp2f((float)(j + 1)) - 1.0f;
    float fc = (cw > ap) ? 1.0f : 0.0f;
    float conc = 4.0f * (float)((j + 1) * (j + 1));
    float rate = (float)(j + 1) / 16.0f;
    float log_norm = lgammaf(conc) - conc * logf(rate);
    float log_un = (conc - 1.0f) * logf(ap) - rate * ap;
    prob = expf(log_un - log_norm) + 1e-8f;
    pe_raw[j * NPOS + pos] = fe;
    pe_raw[(32 + j) * NPOS + pos] = fc;
    pe_raw[(64 + j) * NPOS + pos] = prob;
  }
  // block max -> ONE atomic per block (was 131K contended atomics = 1.1 ms idle stall)
  float m = prob;
#pragma unroll
  for (int off = 32; off > 0; off >>= 1) m = fmaxf(m, __shfl_down(m, off));
  __shared__ float red[4];
  if ((threadIdx.x & 63) == 0) red[threadIdx.x >> 6] = m;
  __syncthreads();
  if (threadIdx.x == 0) {
    m = fmaxf(fmaxf(red[0], red[1]), fmaxf(red[2], red[3]));
    atomicMax(&gmax[j], __float_as_uint(m));
  }
}

// ------------- r_k (bf16, [H][4096][64] t-major) = pe @ Wr, sign-concat fused -------------
__global__ __launch_bounds__(256) void rk_kernel(const float* __restrict__ pe_raw,
                                                 const unsigned* __restrict__ gmax,
                                                 const float* __restrict__ Wr,
                                                 ushort_t* __restrict__ rkb) {
  int col = blockIdx.y;  // 0..511 = h*64+d
  int tid = threadIdx.x;
  __shared__ float w0s[96], w1s[96], ginv[32];
  for (int f = tid; f < 96; f += 256) {
    w0s[f] = Wr[f * HDK + col];
    w1s[f] = Wr[(96 + f) * HDK + col];
  }
  if (tid < 32) ginv[tid] = 1.0f / __uint_as_float(gmax[tid]);
  __syncthreads();
  int pos = blockIdx.x * 256 + tid;
  if (pos >= NPOS) return;
  float sgn = (pos > SEQ - 1) ? 1.0f : ((pos < SEQ - 1) ? -1.0f : 0.0f);
  float acc = 0.0f;
#pragma unroll 8
  for (int f = 0; f < 64; f++) {
    float val = pe_raw[f * NPOS + pos];
    acc = fmaf(val, fmaf(sgn, w1s[f], w0s[f]), acc);
  }
#pragma unroll 8
  for (int f = 64; f < 96; f++) {
    float val = pe_raw[f * NPOS + pos] * ginv[f - 64];
    acc = fmaf(val, fmaf(sgn, w1s[f], w0s[f]), acc);
  }
  rkb[((size_t)(col >> 6) * 4096 + pos) * 64 + (col & 63)] = f2bf(acc);
}

// ---------------- fp32 -> bf16 cast (x) ----------------
__global__ __launch_bounds__(256) void cast_x_kernel(const float* __restrict__ x,
                                                     ushort_t* __restrict__ xb, int n) {
  int i = (blockIdx.x * 256 + threadIdx.x) * 4;
  if (i >= n) return;
  float4 v = *(const float4*)(x + i);
  ushort_t o[4] = {f2bf(v.x), f2bf(v.y), f2bf(v.z), f2bf(v.w)};
  *(unsigned long long*)(xb + i) = *(const unsigned long long*)o;
}

// ---------------- transpose + bf16 cast: W[K][N] fp32 -> WT[N][K] bf16 (+ optional lo) ------
template <bool SPLIT>
__global__ __launch_bounds__(256) void twc_kernel(const float* __restrict__ W,
                                                  ushort_t* __restrict__ WT,
                                                  ushort_t* __restrict__ WTlo,
                                                  int K, int N) {
  __shared__ float t[32][33];
  int k0 = blockIdx.y * 32, n0 = blockIdx.x * 32;
  int tx = threadIdx.x & 31, ty = threadIdx.x >> 5;
#pragma unroll
  for (int p = 0; p < 4; p++) {
    int k = ty + p * 8;
    t[k][tx] = W[(size_t)(k0 + k) * N + n0 + tx];
  }
  __syncthreads();
#pragma unroll
  for (int p = 0; p < 4; p++) {
    int n = ty + p * 8;
    float v = t[tx][n];  // = W[k0+tx][n0+n]
    size_t oidx = (size_t)(n0 + n) * K + k0 + tx;
    ushort_t hi = f2bf(v);
    WT[oidx] = hi;
    if constexpr (SPLIT) WTlo[oidx] = f2bf(v - bf2f(hi));
  }
}

// ---------------- bf16 MFMA GEMM: C[M,N] = A[M,K] @ B^T (B stored [N][K]) ----------------
// 128x128 tile, BK=32, 4 waves (2x2), each wave 64x64 via 16x16x32 MFMA.
// MODE 0: q bf16 [B*S,512] scaled 0.125 | MODE 1: k bf16 [B,H,S,64]
// MODE 2: vT bf16 [B,H,192,S]           | MODE 3: fp32 out + bias
// SPLIT (MODE 3): A2/B2 are lo parts; acc += Ah*Bh + Ah*Bl + Al*Bh  (~fp32 accurate)
template <int MODE, bool SPLIT>
__global__ __launch_bounds__(256, 2) void mfma_gemm(
    const ushort_t* __restrict__ A, const ushort_t* __restrict__ A2,
    const ushort_t* __restrict__ B, const ushort_t* __restrict__ B2,
    const float* __restrict__ bias, void* __restrict__ outv, int N, int K) {
  __shared__ __align__(16) ushort_t As[128 * 32];
  __shared__ __align__(16) ushort_t Bs[128 * 32];
  __shared__ __align__(16) ushort_t As2[SPLIT ? 128 * 32 : 16];
  __shared__ __align__(16) ushort_t Bs2[SPLIT ? 128 * 32 : 16];
  const int tid = threadIdx.x;
  const int lane = tid & 63, l15 = lane & 15, quad = lane >> 4;
  const int wv = tid >> 6;
  const int wm = (wv & 1) * 64, wn = (wv >> 1) * 64;
  const int row0 = blockIdx.y * 128, col0 = blockIdx.x * 128;
  f4v acc[4][4];
#pragma unroll
  for (int i = 0; i < 4; i++)
#pragma unroll
    for (int j = 0; j < 4; j++) acc[i][j] = (f4v)0.0f;

  for (int k0 = 0; k0 < K; k0 += 32) {
    __syncthreads();
#pragma unroll
    for (int p = 0; p < 2; p++) {
      int eoff = (tid + p * 256) * 8;      // element offset into 128x32 tile
      int rr = eoff >> 5, kk = eoff & 31;  // tile row, k within tile
      gl2lds16(A + (size_t)(row0 + rr) * K + k0 + kk, As + eoff);
      gl2lds16(B + (size_t)(col0 + rr) * K + k0 + kk, Bs + eoff);
      if constexpr (SPLIT) {
        gl2lds16(A2 + (size_t)(row0 + rr) * K + k0 + kk, As2 + eoff);
        gl2lds16(B2 + (size_t)(col0 + rr) * K + k0 + kk, Bs2 + eoff);
      }
    }
    __syncthreads();  // compiler drains vmcnt before s_barrier
    bf8v af[4], bfr[4], af2[4], bf2r[4];
#pragma unroll
    for (int t = 0; t < 4; t++) {
      af[t] = *(const bf8v*)(As + (wm + t * 16 + l15) * 32 + quad * 8);
      bfr[t] = *(const bf8v*)(Bs + (wn + t * 16 + l15) * 32 + quad * 8);
      if constexpr (SPLIT) {
        af2[t] = *(const bf8v*)(As2 + (wm + t * 16 + l15) * 32 + quad * 8);
        bf2r[t] = *(const bf8v*)(Bs2 + (wn + t * 16 + l15) * 32 + quad * 8);
      }
    }
#pragma unroll
    for (int mt = 0; mt < 4; mt++)
#pragma unroll
      for (int nt = 0; nt < 4; nt++) {
        acc[mt][nt] = __builtin_amdgcn_mfma_f32_16x16x32_bf16(af[mt], bfr[nt], acc[mt][nt], 0, 0, 0);
        if constexpr (SPLIT) {
          acc[mt][nt] = __builtin_amdgcn_mfma_f32_16x16x32_bf16(af[mt], bf2r[nt], acc[mt][nt], 0, 0, 0);
          acc[mt][nt] = __builtin_amdgcn_mfma_f32_16x16x32_bf16(af2[mt], bfr[nt], acc[mt][nt], 0, 0, 0);
        }
      }
  }
  // epilogue: C row = quad*4+reg, col = l15  (verified C/D layout)
#pragma unroll
  for (int mt = 0; mt < 4; mt++)
#pragma unroll
    for (int reg = 0; reg < 4; reg++) {
      int r = row0 + wm + mt * 16 + quad * 4 + reg;
      int bb = r >> 11, ss = r & (SEQ - 1);
#pragma unroll
      for (int nt = 0; nt < 4; nt++) {
        int c = col0 + wn + nt * 16 + l15;
        float vv = acc[mt][nt][reg];
        if (MODE == 0) {
          ((ushort_t*)outv)[(size_t)r * HDK + c] = f2bf(vv * 0.125f);
        } else if (MODE == 1) {
          int h = c >> 6, d = c & 63;
          ((ushort_t*)outv)[(((size_t)bb * HN + h) * SEQ + ss) * 64 + d] = f2bf(vv);
        } else if (MODE == 2) {
          int h = c / DVC, e = c - h * DVC;
          ((ushort_t*)outv)[(((size_t)bb * HN + h) * DVC + e) * SEQ + ss] = f2bf(vv);
        } else {
          ((float*)outv)[(size_t)r * N + c] = vv + bias[c];
        }
      }
    }
}

// ---------------- flash-style MFMA attention (writes bf16 hi/lo for the Wo GEMM) -----------
__global__ __launch_bounds__(256, 2) void attn_mfma(
    const ushort_t* __restrict__ qb,   // [B*S, 512] bf16, pre-scaled
    const ushort_t* __restrict__ kb,   // [B,H,S,64] bf16
    const ushort_t* __restrict__ vtb,  // [B,H,192,S] bf16
    const ushort_t* __restrict__ rkb,  // [H,4096,64] bf16
    const float* __restrict__ rwb,     // [512]
    const int* __restrict__ mask,      // [B,S]
    ushort_t* __restrict__ attn_hi,    // [B*S, 1536] bf16
    ushort_t* __restrict__ attn_lo)    // [B*S, 1536] bf16
{
  __shared__ __align__(16) char UNI[27648];
  __shared__ ushort_t Vts[192 * LSTR];
  __shared__ ushort_t Pbs[4 * 16 * LSTR];
  __shared__ float mb[64];
  ushort_t* RKs = (ushort_t*)UNI;
  ushort_t* Kts = (ushort_t*)(UNI + 18432);
  float* Rs = (float*)UNI;

  const int i0 = blockIdx.x * 64;
  const int bh = blockIdx.y, b = bh >> 3, h = bh & 7;
  const int tid = threadIdx.x;
  const int wv = tid >> 6, lane = tid & 63;
  const int l15 = lane & 15, quad = lane >> 4;

  bf8v qf[2], qbf[2];
  {
    int qrow = i0 + wv * 16 + l15;
    const ushort_t* qp = qb + (size_t)(b * SEQ + qrow) * HDK + h * 64;
#pragma unroll
    for (int kc = 0; kc < 2; kc++) {
      bf8v qv = *(const bf8v*)(qp + kc * 32 + quad * 8);
      qf[kc] = qv;
      bf8v t;
#pragma unroll
      for (int j = 0; j < 8; j++) {
        float f = bf2f((ushort_t)qv[j]) + rwb[h * 64 + kc * 32 + quad * 8 + j];
        t[j] = (short)f2bf(f);
      }
      qbf[kc] = t;
    }
  }

  f4v Of[12];
#pragma unroll
  for (int se = 0; se < 12; se++) Of[se] = (f4v)0.0f;
  float m_i[4] = {-INFINITY, -INFINITY, -INFINITY, -INFINITY};
  float l_i[4] = {0.f, 0.f, 0.f, 0.f};

  for (int j0 = 0; j0 < SEQ; j0 += 64) {
    __syncthreads();
    {
      const int U0 = j0 - i0 + 1984;
#pragma unroll
      for (int r = 0; r < 2; r++) {
        int idx = tid + r * 256, row = idx >> 3, seg = idx & 7;
        *(bf8v*)(Kts + row * LSTR + seg * 8) =
            *(const bf8v*)(kb + ((size_t)bh * SEQ + j0 + row) * 64 + seg * 8);
      }
#pragma unroll
      for (int r = 0; r < 6; r++) {
        int idx = tid + r * 256, row = idx >> 3, seg = idx & 7;
        *(bf8v*)(Vts + row * LSTR + seg * 8) =
            *(const bf8v*)(vtb + ((size_t)bh * DVC + row) * SEQ + j0 + seg * 8);
      }
#pragma unroll
      for (int r = 0; r < 4; r++) {
        int idx = tid + r * 256, row = idx >> 3, seg = idx & 7;
        *(bf8v*)(RKs + row * LSTR + seg * 8) =
            *(const bf8v*)(rkb + ((size_t)h * 4096 + U0 + row) * 64 + seg * 8);
      }
      if (tid < 64) mb[tid] = mask[b * SEQ + j0 + tid] ? 0.f : -1.0f;
    }
    __syncthreads();

    f4v Sf[4];
#pragma unroll
    for (int s = 0; s < 4; s++) {
      Sf[s] = (f4v)0.0f;
#pragma unroll
      for (int kc = 0; kc < 2; kc++) {
        bf8v kf = *(const bf8v*)(Kts + (s * 16 + l15) * LSTR + kc * 32 + quad * 8);
        Sf[s] = __builtin_amdgcn_mfma_f32_16x16x32_bf16(qf[kc], kf, Sf[s], 0, 0, 0);
      }
    }
    f4v Rf[5];
    const int tb = 48 - 16 * wv;
#pragma unroll
    for (int u = 0; u < 5; u++) {
      Rf[u] = (f4v)0.0f;
#pragma unroll
      for (int kc = 0; kc < 2; kc++) {
        bf8v rf = *(const bf8v*)(RKs + (tb + u * 16 + l15) * LSTR + kc * 32 + quad * 8);
        Rf[u] = __builtin_amdgcn_mfma_f32_16x16x32_bf16(qbf[kc], rf, Rf[u], 0, 0, 0);
      }
    }
    __syncthreads();
    float* Rw = Rs + wv * 16 * RSTR;
#pragma unroll
    for (int u = 0; u < 5; u++)
#pragma unroll
      for (int reg = 0; reg < 4; reg++)
        Rw[(quad * 4 + reg) * RSTR + u * 16 + l15] = Rf[u][reg];

#pragma unroll
    for (int s = 0; s < 4; s++)
#pragma unroll
      for (int reg = 0; reg < 4; reg++) {
        int r = quad * 4 + reg;
        int c = s * 16 + l15;
        float li = Sf[s][reg] + Rw[r * RSTR + (c - r + 15)];
        Sf[s][reg] = (mb[c] == 0.f) ? li : -1e9f;
      }

#pragma unroll
    for (int reg = 0; reg < 4; reg++) {
      float t = fmaxf(fmaxf(Sf[0][reg], Sf[1][reg]), fmaxf(Sf[2][reg], Sf[3][reg]));
      t = fmaxf(t, __shfl_xor(t, 1));
      t = fmaxf(t, __shfl_xor(t, 2));
      t = fmaxf(t, __shfl_xor(t, 4));
      t = fmaxf(t, __shfl_xor(t, 8));
      float mn = fmaxf(m_i[reg], t);
      float alpha = __expf(m_i[reg] - mn);
      m_i[reg] = mn;
      l_i[reg] *= alpha;
#pragma unroll
      for (int se = 0; se < 12; se++) Of[se][reg] *= alpha;
      float rs = 0.f;
#pragma unroll
      for (int s = 0; s < 4; s++) {
        float p = __expf(Sf[s][reg] - mn);
        Sf[s][reg] = p;
        rs += p;
      }
      rs += __shfl_xor(rs, 1);
      rs += __shfl_xor(rs, 2);
      rs += __shfl_xor(rs, 4);
      rs += __shfl_xor(rs, 8);
      l_i[reg] += rs;
#pragma unroll
      for (int s = 0; s < 4; s++)
        Pbs[(wv * 16 + quad * 4 + reg) * LSTR + s * 16 + l15] = f2bf(Sf[s][reg]);
    }

    bf8v pa[2];
#pragma unroll
    for (int kc = 0; kc < 2; kc++)
      pa[kc] = *(const bf8v*)(Pbs + (wv * 16 + l15) * LSTR + kc * 32 + quad * 8);
#pragma unroll
    for (int se = 0; se < 12; se++) {
#pragma unroll
      for (int kc = 0; kc < 2; kc++) {
        bf8v vf = *(const bf8v*)(Vts + (se * 16 + l15) * LSTR + kc * 32 + quad * 8);
        Of[se] = __builtin_amdgcn_mfma_f32_16x16x32_bf16(pa[kc], vf, Of[se], 0, 0, 0);
      }
    }
  }

#pragma unroll
  for (int reg = 0; reg < 4; reg++) {
    float inv = 1.0f / l_i[reg];
    int row = i0 + wv * 16 + quad * 4 + reg;
    size_t base = (size_t)(b * SEQ + row) * HDV + h * DVC;
#pragma unroll
    for (int se = 0; se < 12; se++) {
      float val = Of[se][reg] * inv;
      ushort_t hi = f2bf(val);
      attn_hi[base + se * 16 + l15] = hi;
      attn_lo[base + se * 16 + l15] = f2bf(val - bf2f(hi));
    }
  }
}

extern "C" void kernel_launch(void* const* d_in, const int* in_sizes, int n_in,
                              void* d_out, int out_size, void* d_ws, size_t ws_size,
                              hipStream_t stream) {
  const float* x    = (const float*)d_in[0];
  const int*   mask = (const int*)d_in[1];
  const float* Wq   = (const float*)d_in[2];
  const float* Wk   = (const float*)d_in[3];
  const float* Wv   = (const float*)d_in[4];
  const float* Wr   = (const float*)d_in[5];
  const float* rwb  = (const float*)d_in[6];
  const float* Wo   = (const float*)d_in[7];
  const float* bo   = (const float*)d_in[8];
  float* out = (float*)d_out;

  char* wsb = (char*)d_ws;
  float* pe_raw   = (float*)wsb;     wsb += (size_t)96 * NPOS * 4;       // 1,572,480
  unsigned* gmax  = (unsigned*)wsb;  wsb += 128;
  ushort_t* xb    = (ushort_t*)wsb;  wsb += (size_t)BN * SEQ * CDIM * 2; // 12.6 MB (aliased by attn_hi)
  ushort_t* qb    = (ushort_t*)wsb;  wsb += (size_t)BN * SEQ * HDK * 2;
  ushort_t* kb    = (ushort_t*)wsb;  wsb += (size_t)BN * SEQ * HDK * 2;
  ushort_t* vtb   = (ushort_t*)wsb;  wsb += (size_t)BN * SEQ * HDV * 2;
  ushort_t* rkb   = (ushort_t*)wsb;  wsb += (size_t)HN * 4096 * 64 * 2;
  ushort_t* WqT   = (ushort_t*)wsb;  wsb += (size_t)HDK * CDIM * 2;
  ushort_t* WkT   = (ushort_t*)wsb;  wsb += (size_t)HDK * CDIM * 2;
  ushort_t* WvT   = (ushort_t*)wsb;  wsb += (size_t)HDV * CDIM * 2;
  ushort_t* WoTh  = (ushort_t*)wsb;  wsb += (size_t)HDV * CDIM * 2;
  ushort_t* WoTl  = (ushort_t*)wsb;  wsb += (size_t)HDV * CDIM * 2;
  ushort_t* attnl = (ushort_t*)wsb;  wsb += (size_t)BN * SEQ * HDV * 2;
  ushort_t* attnh = xb;  // xb dead after v-projection; attn runs after -> safe alias
  // total ~69 MB

  hipMemsetAsync(gmax, 0, 32 * sizeof(unsigned), stream);
  pos_feat_kernel<<<dim3(16, 32), 256, 0, stream>>>(pe_raw, gmax);
  rk_kernel<<<dim3(16, HDK), 256, 0, stream>>>(pe_raw, gmax, Wr, rkb);
  cast_x_kernel<<<(BN * SEQ * CDIM / 4 + 255) / 256, 256, 0, stream>>>(x, xb, BN * SEQ * CDIM);
  twc_kernel<false><<<dim3(HDK / 32, CDIM / 32), 256, 0, stream>>>(Wq, WqT, nullptr, CDIM, HDK);
  twc_kernel<false><<<dim3(HDK / 32, CDIM / 32), 256, 0, stream>>>(Wk, WkT, nullptr, CDIM, HDK);
  twc_kernel<false><<<dim3(HDV / 32, CDIM / 32), 256, 0, stream>>>(Wv, WvT, nullptr, CDIM, HDV);
  twc_kernel<true ><<<dim3(HDV / 32, CDIM / 32), 256, 0, stream>>>(Wo, WoTh, WoTl, CDIM, HDV);
  mfma_gemm<0, false><<<dim3(HDK / 128, BN * SEQ / 128), 256, 0, stream>>>(xb, nullptr, WqT, nullptr, nullptr, qb, HDK, CDIM);
  mfma_gemm<1, false><<<dim3(HDK / 128, BN * SEQ / 128), 256, 0, stream>>>(xb, nullptr, WkT, nullptr, nullptr, kb, HDK, CDIM);
  mfma_gemm<2, false><<<dim3(HDV / 128, BN * SEQ / 128), 256, 0, stream>>>(xb, nullptr, WvT, nullptr, nullptr, vtb, HDV, CDIM);
  attn_mfma<<<dim3(SEQ / 64, BN * HN), 256, 0, stream>>>(qb, kb, vtb, rkb, rwb, mask, attnh, attnl);
  mfma_gemm<3, true ><<<dim3(HDV / 128, BN * SEQ / 128), 256, 0, stream>>>(attnh, attnl, WoTh, WoTl, bo, out, HDV, CDIM);
}

// Round 4
// 415.271 us; speedup vs baseline: 12.5994x; 1.1239x over previous
//
#include <hip/hip_runtime.h>
#include <math.h>

#define SEQ 2048
#define CDIM 1536
#define HN 8
#define DVC 192
#define BN 2
#define NPOS 4095   // 2*SEQ-1
#define HDK 512     // H*DK
#define HDV 1536    // H*DV
#define PSTR 72     // Pbs LDS stride (shorts)

typedef __attribute__((ext_vector_type(8))) short bf8v;   // 8 bf16 (4 VGPRs)
typedef __attribute__((ext_vector_type(4))) float f4v;    // MFMA C/D frag
typedef unsigned short ushort_t;

static __device__ __forceinline__ float bf2f(ushort_t h) {
  union { unsigned int u; float f; } c; c.u = ((unsigned int)h) << 16; return c.f;
}
static __device__ __forceinline__ ushort_t f2bf(float f) {
  union { float f; unsigned int u; } c; c.f = f;
  return (ushort_t)((c.u + 0x7fffu + ((c.u >> 16) & 1u)) >> 16);
}
static __device__ __forceinline__ void gl2lds16(const void* g, void* l) {
  __builtin_amdgcn_global_load_lds((const __attribute__((address_space(1))) unsigned int*)g,
                                   (__attribute__((address_space(3))) unsigned int*)l,
                                   16, 0, 0);
}

// ================= fused prep: pos-features + cast x + 5 weight transposes =================
// block ranges: [0,512) pos_feat | [512,6656) cast_x | then twc tiles:
//   Wq->WTqkv rows 0-511 (768), Wk->rows 512-1023 (768), Wv->rows 1024-2559 (2304),
//   Wo->WoTh/WoTl split (2304), Wr->WrT (96)
#define PF_B   512
#define CAST_B 6144
#define TWQ_B  768
#define TWK_B  768
#define TWV_B  2304
#define TWO_B  2304
#define TWR_B  96
#define PREP_BLOCKS (PF_B + CAST_B + TWQ_B + TWK_B + TWV_B + TWO_B + TWR_B)

__device__ __forceinline__ void twc_tile(const float* __restrict__ W, ushort_t* __restrict__ WT,
                                         ushort_t* __restrict__ WTlo, int K, int N, int tile,
                                         float (*tls)[33], int tid) {
  int ntn = N >> 5;
  int nt = tile % ntn, kt = tile / ntn;
  int k0 = kt * 32, n0 = nt * 32;
  int tx = tid & 31, ty = tid >> 5;
#pragma unroll
  for (int p = 0; p < 4; p++) tls[ty + p * 8][tx] = W[(size_t)(k0 + ty + p * 8) * N + n0 + tx];
  __syncthreads();
#pragma unroll
  for (int p = 0; p < 4; p++) {
    int n = ty + p * 8;
    float v = tls[tx][n];
    size_t oidx = (size_t)(n0 + n) * K + k0 + tx;
    ushort_t hi = f2bf(v);
    WT[oidx] = hi;
    if (WTlo) WTlo[oidx] = f2bf(v - bf2f(hi));
  }
}

__global__ __launch_bounds__(256) void prep_kernel(
    const float* __restrict__ x, const float* __restrict__ Wq, const float* __restrict__ Wk,
    const float* __restrict__ Wv, const float* __restrict__ Wo, const float* __restrict__ Wr,
    float* __restrict__ pe_raw, unsigned* __restrict__ gmax, ushort_t* __restrict__ xb,
    ushort_t* __restrict__ WTqkv, ushort_t* __restrict__ WoTh, ushort_t* __restrict__ WoTl,
    ushort_t* __restrict__ WrT) {
  __shared__ float tls[32][33];
  int blk = blockIdx.x, tid = threadIdx.x;
  if (blk < PF_B) {
    // pos features: j uniform per block -> single atomic
    int j = blk >> 4;
    int pos = (blk & 15) * 256 + tid;
    float prob = 0.0f;
    if (pos < NPOS) {
      float ap = fabsf((float)(pos - (SEQ - 1)));
      float hl = exp2f(3.0f + 8.0f * (float)j / 31.0f);
      float fe = exp2f(-ap / hl);
      float cw = exp2f((float)(j + 1)) - 1.0f;
      float fc = (cw > ap) ? 1.0f : 0.0f;
      float conc = 4.0f * (float)((j + 1) * (j + 1));
      float rate = (float)(j + 1) / 16.0f;
      float log_norm = lgammaf(conc) - conc * logf(rate);
      float log_un = (conc - 1.0f) * logf(ap) - rate * ap;
      prob = expf(log_un - log_norm) + 1e-8f;
      pe_raw[pos * 96 + j] = fe;
      pe_raw[pos * 96 + 32 + j] = fc;
      pe_raw[pos * 96 + 64 + j] = prob;
    }
    float m = prob;
#pragma unroll
    for (int off = 32; off > 0; off >>= 1) m = fmaxf(m, __shfl_down(m, off));
    __shared__ float red[4];
    if ((tid & 63) == 0) red[tid >> 6] = m;
    __syncthreads();
    if (tid == 0) {
      m = fmaxf(fmaxf(red[0], red[1]), fmaxf(red[2], red[3]));
      atomicMax(&gmax[j], __float_as_uint(m));
    }
  } else if (blk < PF_B + CAST_B) {
    int i = ((blk - PF_B) * 256 + tid) * 4;
    float4 v = *(const float4*)(x + i);
    ushort_t o[4] = {f2bf(v.x), f2bf(v.y), f2bf(v.z), f2bf(v.w)};
    *(unsigned long long*)(xb + i) = *(const unsigned long long*)o;
  } else if (blk < PF_B + CAST_B + TWQ_B) {
    twc_tile(Wq, WTqkv + 0 * (size_t)CDIM, nullptr, CDIM, HDK, blk - (PF_B + CAST_B), tls, tid);
  } else if (blk < PF_B + CAST_B + TWQ_B + TWK_B) {
    twc_tile(Wk, WTqkv + 512 * (size_t)CDIM, nullptr, CDIM, HDK, blk - (PF_B + CAST_B + TWQ_B), tls, tid);
  } else if (blk < PF_B + CAST_B + TWQ_B + TWK_B + TWV_B) {
    twc_tile(Wv, WTqkv + 1024 * (size_t)CDIM, nullptr, CDIM, HDV, blk - (PF_B + CAST_B + TWQ_B + TWK_B), tls, tid);
  } else if (blk < PF_B + CAST_B + TWQ_B + TWK_B + TWV_B + TWO_B) {
    twc_tile(Wo, WoTh, WoTl, CDIM, HDV, blk - (PF_B + CAST_B + TWQ_B + TWK_B + TWV_B), tls, tid);
  } else {
    twc_tile(Wr, WrT, nullptr, 192, HDK, blk - (PF_B + CAST_B + TWQ_B + TWK_B + TWV_B + TWO_B), tls, tid);
  }
}

// ============ pe_bf [4096][192] bf16: normalize gamma, apply sign-concat ============
__global__ __launch_bounds__(256) void pe_norm_kernel(const float* __restrict__ pe_raw,
                                                      const unsigned* __restrict__ gmax,
                                                      ushort_t* __restrict__ pe_bf) {
  int idx = blockIdx.x * 256 + threadIdx.x;  // over 4096*96
  int pos = idx / 96, f = idx - pos * 96;
  float val = 0.0f, sval = 0.0f;
  if (pos < NPOS) {
    val = pe_raw[pos * 96 + f];
    if (f >= 64) val *= 1.0f / __uint_as_float(gmax[f - 64]);
    float sgn = (pos > SEQ - 1) ? 1.0f : ((pos < SEQ - 1) ? -1.0f : 0.0f);
    sval = sgn * val;
  }
  pe_bf[pos * 192 + f] = f2bf(val);
  pe_bf[pos * 192 + 96 + f] = f2bf(sval);
}

// ================= bf16 MFMA GEMM, 128x128xBK32, XOR-swizzled LDS =================
// MODE 0 (QKV): c<512 -> qb*0.125 ; c<1024 -> kb[B,H,S,64] ; else vtb[B,H,192,S]
// MODE 1 (RK):  rkb[(h*4096+pos)*64+d]
// MODE 2 (OUT): fp32 out + bias, SPLIT hi/lo inputs
template <int MODE, bool SPLIT>
__global__ __launch_bounds__(256, 2) void mfma_gemm(
    const ushort_t* __restrict__ A, const ushort_t* __restrict__ A2,
    const ushort_t* __restrict__ B, const ushort_t* __restrict__ B2,
    const float* __restrict__ bias, void* __restrict__ out0, void* __restrict__ out1,
    void* __restrict__ out2, int K) {
  __shared__ __align__(16) ushort_t As[128 * 32];
  __shared__ __align__(16) ushort_t Bs[128 * 32];
  __shared__ __align__(16) ushort_t As2[SPLIT ? 128 * 32 : 16];
  __shared__ __align__(16) ushort_t Bs2[SPLIT ? 128 * 32 : 16];
  const int tid = threadIdx.x;
  const int lane = tid & 63, l15 = lane & 15, quad = lane >> 4;
  const int wv = tid >> 6;
  const int wm = (wv & 1) * 64, wn = (wv >> 1) * 64;
  const int row0 = blockIdx.y * 128, col0 = blockIdx.x * 128;
  f4v acc[4][4];
#pragma unroll
  for (int i = 0; i < 4; i++)
#pragma unroll
    for (int j = 0; j < 4; j++) acc[i][j] = (f4v)0.0f;

  for (int k0 = 0; k0 < K; k0 += 32) {
    __syncthreads();
#pragma unroll
    for (int p = 0; p < 2; p++) {
      int idx = tid + p * 256;
      int rr = idx >> 2, sc = idx & 3;
      int gc = (sc ^ ((rr >> 1) & 3)) << 3;  // swizzled source chunk (shorts)
      gl2lds16(A + (size_t)(row0 + rr) * K + k0 + gc, As + idx * 8);
      gl2lds16(B + (size_t)(col0 + rr) * K + k0 + gc, Bs + idx * 8);
      if constexpr (SPLIT) {
        gl2lds16(A2 + (size_t)(row0 + rr) * K + k0 + gc, As2 + idx * 8);
        gl2lds16(B2 + (size_t)(col0 + rr) * K + k0 + gc, Bs2 + idx * 8);
      }
    }
    __syncthreads();
    bf8v af[4], bfr[4], af2[4], bf2r[4];
#pragma unroll
    for (int t = 0; t < 4; t++) {
      int lrA = wm + t * 16 + l15;
      int lrB = wn + t * 16 + l15;
      int cA = (quad ^ ((lrA >> 1) & 3)) << 3;
      int cB = (quad ^ ((lrB >> 1) & 3)) << 3;
      af[t] = *(const bf8v*)(As + lrA * 32 + cA);
      bfr[t] = *(const bf8v*)(Bs + lrB * 32 + cB);
      if constexpr (SPLIT) {
        af2[t] = *(const bf8v*)(As2 + lrA * 32 + cA);
        bf2r[t] = *(const bf8v*)(Bs2 + lrB * 32 + cB);
      }
    }
#pragma unroll
    for (int mt = 0; mt < 4; mt++)
#pragma unroll
      for (int nt = 0; nt < 4; nt++) {
        acc[mt][nt] = __builtin_amdgcn_mfma_f32_16x16x32_bf16(af[mt], bfr[nt], acc[mt][nt], 0, 0, 0);
        if constexpr (SPLIT) {
          acc[mt][nt] = __builtin_amdgcn_mfma_f32_16x16x32_bf16(af[mt], bf2r[nt], acc[mt][nt], 0, 0, 0);
          acc[mt][nt] = __builtin_amdgcn_mfma_f32_16x16x32_bf16(af2[mt], bfr[nt], acc[mt][nt], 0, 0, 0);
        }
      }
  }
#pragma unroll
  for (int mt = 0; mt < 4; mt++)
#pragma unroll
    for (int reg = 0; reg < 4; reg++) {
      int r = row0 + wm + mt * 16 + quad * 4 + reg;
      int bb = r >> 11, ss = r & (SEQ - 1);
#pragma unroll
      for (int nt = 0; nt < 4; nt++) {
        int c = col0 + wn + nt * 16 + l15;
        float vv = acc[mt][nt][reg];
        if (MODE == 0) {
          if (c < 512) {
            ((ushort_t*)out0)[(size_t)r * HDK + c] = f2bf(vv * 0.125f);
          } else if (c < 1024) {
            int cc = c - 512, h = cc >> 6, d = cc & 63;
            ((ushort_t*)out1)[(((size_t)bb * HN + h) * SEQ + ss) * 64 + d] = f2bf(vv);
          } else {
            int cc = c - 1024, h = cc / DVC, e = cc - h * DVC;
            ((ushort_t*)out2)[(((size_t)bb * HN + h) * DVC + e) * SEQ + ss] = f2bf(vv);
          }
        } else if (MODE == 1) {
          int h = c >> 6, d = c & 63;
          ((ushort_t*)out0)[((size_t)h * 4096 + r) * 64 + d] = f2bf(vv);
        } else {
          ((float*)out0)[(size_t)r * HDV + c] = vv + bias[c];
        }
      }
    }
}

// ================= flash MFMA attention, swizzled LDS + bpermute band =================
// grid (32, SPLITKV?32:16); Q-tile 64 rows, 4 waves; per-tile: QK^T + banded rel + PV
template <bool SPLITKV>
__global__ __launch_bounds__(256, 3) void attn_mfma(
    const ushort_t* __restrict__ qb, const ushort_t* __restrict__ kb,
    const ushort_t* __restrict__ vtb, const ushort_t* __restrict__ rkb,
    const float* __restrict__ rwb, const int* __restrict__ mask,
    ushort_t* __restrict__ attn_hi, ushort_t* __restrict__ attn_lo,
    float* __restrict__ Opart, float* __restrict__ ml) {
  __shared__ __align__(16) ushort_t Vts[192 * 64];   // 24576 B
  __shared__ __align__(16) ushort_t UNI[192 * 64];   // RKs[128*64] | Kts[64*64]; Pbs aliases RKs
  __shared__ float mb[64];
  ushort_t* RKs = UNI;
  ushort_t* Kts = UNI + 128 * 64;
  ushort_t* Pbs = UNI;  // stride PSTR, 9216 B < RKs region

  const int i0 = blockIdx.x * 64;
  const int by = blockIdx.y;
  const int bh = SPLITKV ? (by & 15) : by;
  const int half = SPLITKV ? (by >> 4) : 0;
  const int b = bh >> 3, h = bh & 7;
  const int tid = threadIdx.x;
  const int wv = tid >> 6, lane = tid & 63;
  const int l15 = lane & 15, quad = lane >> 4;

  bf8v qf[2], qbf[2];
  {
    int qrow = i0 + wv * 16 + l15;
    const ushort_t* qp = qb + (size_t)(b * SEQ + qrow) * HDK + h * 64;
#pragma unroll
    for (int kc = 0; kc < 2; kc++) {
      bf8v qv = *(const bf8v*)(qp + kc * 32 + quad * 8);
      qf[kc] = qv;
      bf8v t;
#pragma unroll
      for (int j = 0; j < 8; j++) {
        float f = bf2f((ushort_t)qv[j]) + rwb[h * 64 + kc * 32 + quad * 8 + j];
        t[j] = (short)f2bf(f);
      }
      qbf[kc] = t;
    }
  }

  f4v Of[12];
#pragma unroll
  for (int se = 0; se < 12; se++) Of[se] = (f4v)0.0f;
  float m_i[4] = {-INFINITY, -INFINITY, -INFINITY, -INFINITY};
  float l_i[4] = {0.f, 0.f, 0.f, 0.f};

  const int j0beg = SPLITKV ? half * (SEQ / 2) : 0;
  const int j0end = SPLITKV ? j0beg + SEQ / 2 : SEQ;
  const int tb = 48 - 16 * wv;

  for (int j0 = j0beg; j0 < j0end; j0 += 64) {
    __syncthreads();  // prior readers (pa/Vts) done before staging overwrites
    {
      const int U0 = j0 - i0 + 1984;
#pragma unroll
      for (int r = 0; r < 2; r++) {
        int idx = tid + r * 256, row = idx >> 3, sc = idx & 7;
        gl2lds16(kb + ((size_t)bh * SEQ + j0 + row) * 64 + ((sc ^ (row & 7)) << 3), Kts + idx * 8);
      }
#pragma unroll
      for (int r = 0; r < 6; r++) {
        int idx = tid + r * 256, row = idx >> 3, sc = idx & 7;
        gl2lds16(vtb + ((size_t)bh * DVC + row) * SEQ + j0 + ((sc ^ (row & 7)) << 3), Vts + idx * 8);
      }
#pragma unroll
      for (int r = 0; r < 4; r++) {
        int idx = tid + r * 256, row = idx >> 3, sc = idx & 7;
        gl2lds16(rkb + ((size_t)h * 4096 + U0 + row) * 64 + ((sc ^ (row & 7)) << 3), RKs + idx * 8);
      }
      if (tid < 64) mb[tid] = mask[b * SEQ + j0 + tid] ? 0.f : -1e9f;
    }
    __syncthreads();  // barrier drains vmcnt -> LDS ready

    // content logits
    f4v Sf[4];
#pragma unroll
    for (int s = 0; s < 4; s++) {
      Sf[s] = (f4v)0.0f;
#pragma unroll
      for (int kc = 0; kc < 2; kc++) {
        int row = s * 16 + l15;
        bf8v kf = *(const bf8v*)(Kts + row * 64 + ((((kc << 2) | quad) ^ (row & 7)) << 3));
        Sf[s] = __builtin_amdgcn_mfma_f32_16x16x32_bf16(qf[kc], kf, Sf[s], 0, 0, 0);
      }
    }
    // rel logits over 80-row window
    f4v Rf[5];
#pragma unroll
    for (int u = 0; u < 5; u++) {
      Rf[u] = (f4v)0.0f;
#pragma unroll
      for (int kc = 0; kc < 2; kc++) {
        int row = tb + u * 16 + l15;
        bf8v rf = *(const bf8v*)(RKs + row * 64 + ((((kc << 2) | quad) ^ (row & 7)) << 3));
        Rf[u] = __builtin_amdgcn_mfma_f32_16x16x32_bf16(qbf[kc], rf, Rf[u], 0, 0, 0);
      }
    }
    __syncthreads();  // all waves done reading UNI; P may now alias it

    // band extraction via bpermute: S[r][c] += R[r][c-r+15], r=quad*4+reg, c=s*16+l15
    float mv[4];
#pragma unroll
    for (int s = 0; s < 4; s++) mv[s] = mb[s * 16 + l15];
#pragma unroll
    for (int reg = 0; reg < 4; reg++) {
      int delta = l15 - (quad << 2) - reg + 15;  // [0,30]
      int srcl = (quad << 4) | (delta & 15);
      float sh0 = __shfl(Rf[0][reg], srcl, 64);
      float sh1 = __shfl(Rf[1][reg], srcl, 64);
      float sh2 = __shfl(Rf[2][reg], srcl, 64);
      float sh3 = __shfl(Rf[3][reg], srcl, 64);
      float sh4 = __shfl(Rf[4][reg], srcl, 64);
      bool hib = delta >= 16;
      Sf[0][reg] += (hib ? sh1 : sh0) + mv[0];
      Sf[1][reg] += (hib ? sh2 : sh1) + mv[1];
      Sf[2][reg] += (hib ? sh3 : sh2) + mv[2];
      Sf[3][reg] += (hib ? sh4 : sh3) + mv[3];
    }

    // online softmax (+ alpha-skip when max unchanged across whole wave)
#pragma unroll
    for (int reg = 0; reg < 4; reg++) {
      float t = fmaxf(fmaxf(Sf[0][reg], Sf[1][reg]), fmaxf(Sf[2][reg], Sf[3][reg]));
      t = fmaxf(t, __shfl_xor(t, 1));
      t = fmaxf(t, __shfl_xor(t, 2));
      t = fmaxf(t, __shfl_xor(t, 4));
      t = fmaxf(t, __shfl_xor(t, 8));
      float mn = fmaxf(m_i[reg], t);
      float alpha = __expf(m_i[reg] - mn);
      m_i[reg] = mn;
      if (__ballot(alpha != 1.0f)) {
        l_i[reg] *= alpha;
#pragma unroll
        for (int se = 0; se < 12; se++) Of[se][reg] *= alpha;
      }
      float rs = 0.f;
#pragma unroll
      for (int s = 0; s < 4; s++) {
        float p = __expf(Sf[s][reg] - mn);
        rs += p;
        Pbs[(wv * 16 + quad * 4 + reg) * PSTR + s * 16 + l15] = f2bf(p);
      }
      rs += __shfl_xor(rs, 1);
      rs += __shfl_xor(rs, 2);
      rs += __shfl_xor(rs, 4);
      rs += __shfl_xor(rs, 8);
      l_i[reg] += rs;
    }

    // PV
    bf8v pa[2];
#pragma unroll
    for (int kc = 0; kc < 2; kc++)
      pa[kc] = *(const bf8v*)(Pbs + (wv * 16 + l15) * PSTR + kc * 32 + quad * 8);
#pragma unroll
    for (int se = 0; se < 12; se++) {
#pragma unroll
      for (int kc = 0; kc < 2; kc++) {
        int row = se * 16 + l15;
        bf8v vf = *(const bf8v*)(Vts + row * 64 + ((((kc << 2) | quad) ^ (row & 7)) << 3));
        Of[se] = __builtin_amdgcn_mfma_f32_16x16x32_bf16(pa[kc], vf, Of[se], 0, 0, 0);
      }
    }
  }

#pragma unroll
  for (int reg = 0; reg < 4; reg++) {
    int row = i0 + wv * 16 + quad * 4 + reg;
    int rg = b * SEQ + row;
    if constexpr (SPLITKV) {
      float* Op = Opart + ((size_t)(half * 4096 + rg)) * HDV + h * DVC;
#pragma unroll
      for (int se = 0; se < 12; se++) Op[se * 16 + l15] = Of[se][reg];
      if (l15 == 0) {
        size_t mlb = (((size_t)half * 4096 + rg) * HN + h) * 2;
        ml[mlb] = m_i[reg];
        ml[mlb + 1] = l_i[reg];
      }
    } else {
      float inv = 1.0f / l_i[reg];
      size_t base = (size_t)rg * HDV + h * DVC;
#pragma unroll
      for (int se = 0; se < 12; se++) {
        float val = Of[se][reg] * inv;
        ushort_t hi = f2bf(val);
        attn_hi[base + se * 16 + l15] = hi;
        attn_lo[base + se * 16 + l15] = f2bf(val - bf2f(hi));
      }
    }
  }
}

// ================= combine the two KV halves =================
__global__ __launch_bounds__(256) void combine_kernel(const float* __restrict__ Opart,
                                                      const float* __restrict__ ml,
                                                      ushort_t* __restrict__ attn_hi,
                                                      ushort_t* __restrict__ attn_lo) {
  int i4 = blockIdx.x * 256 + threadIdx.x;  // over 4096*384
  int rg = i4 / 384, c4 = (i4 - rg * 384) * 4;
  int h = c4 / DVC;
  size_t mlb0 = ((size_t)rg * HN + h) * 2;
  size_t mlb1 = (((size_t)4096 + rg) * HN + h) * 2;
  float m0 = ml[mlb0], l0 = ml[mlb0 + 1];
  float m1 = ml[mlb1], l1 = ml[mlb1 + 1];
  float M = fmaxf(m0, m1);
  float w0 = __expf(m0 - M), w1 = __expf(m1 - M);
  float inv = 1.0f / (l0 * w0 + l1 * w1);
  float4 O0 = *(const float4*)(Opart + (size_t)rg * HDV + c4);
  float4 O1 = *(const float4*)(Opart + ((size_t)4096 + rg) * HDV + c4);
  float o[4] = {(O0.x * w0 + O1.x * w1) * inv, (O0.y * w0 + O1.y * w1) * inv,
                (O0.z * w0 + O1.z * w1) * inv, (O0.w * w0 + O1.w * w1) * inv};
  ushort_t hi[4], lo[4];
#pragma unroll
  for (int q = 0; q < 4; q++) {
    hi[q] = f2bf(o[q]);
    lo[q] = f2bf(o[q] - bf2f(hi[q]));
  }
  size_t base = (size_t)rg * HDV + c4;
  *(unsigned long long*)(attn_hi + base) = *(const unsigned long long*)hi;
  *(unsigned long long*)(attn_lo + base) = *(const unsigned long long*)lo;
}

extern "C" void kernel_launch(void* const* d_in, const int* in_sizes, int n_in,
                              void* d_out, int out_size, void* d_ws, size_t ws_size,
                              hipStream_t stream) {
  const float* x    = (const float*)d_in[0];
  const int*   mask = (const int*)d_in[1];
  const float* Wq   = (const float*)d_in[2];
  const float* Wk   = (const float*)d_in[3];
  const float* Wv   = (const float*)d_in[4];
  const float* Wr   = (const float*)d_in[5];
  const float* rwb  = (const float*)d_in[6];
  const float* Wo   = (const float*)d_in[7];
  const float* bo   = (const float*)d_in[8];
  float* out = (float*)d_out;

  char* wsb = (char*)d_ws;
  size_t o = 0;
  auto al = [](size_t v) { return (v + 255) & ~(size_t)255; };
#define CARVE(ptr_t, name, bytes) ptr_t name = (ptr_t)(wsb + o); o = al(o + (bytes));
  CARVE(float*, pe_raw, (size_t)4096 * 96 * 4)
  CARVE(unsigned*, gmax, 128)
  CARVE(ushort_t*, pe_bf, (size_t)4096 * 192 * 2)
  CARVE(ushort_t*, WrT, (size_t)HDK * 192 * 2)
  CARVE(ushort_t*, xb, (size_t)BN * SEQ * CDIM * 2)
  CARVE(ushort_t*, WTqkv, (size_t)2560 * CDIM * 2)
  CARVE(ushort_t*, WoTh, (size_t)HDV * CDIM * 2)
  CARVE(ushort_t*, WoTl, (size_t)HDV * CDIM * 2)
  CARVE(ushort_t*, qb, (size_t)BN * SEQ * HDK * 2)
  CARVE(ushort_t*, kb, (size_t)BN * SEQ * HDK * 2)
  CARVE(ushort_t*, vtb, (size_t)BN * SEQ * HDV * 2)
  CARVE(ushort_t*, rkb, (size_t)HN * 4096 * 64 * 2)
  CARVE(ushort_t*, attnl, (size_t)BN * SEQ * HDV * 2)
  ushort_t* attnh = xb;  // xb dead after QKV gemm
  size_t base_total = o;
  CARVE(float*, Opart, (size_t)2 * 4096 * HDV * 4)
  CARVE(float*, ml, (size_t)2 * 4096 * HN * 2 * 4)
  bool dosplit = (o <= ws_size);
  (void)base_total;

  hipMemsetAsync(gmax, 0, 32 * sizeof(unsigned), stream);
  prep_kernel<<<PREP_BLOCKS, 256, 0, stream>>>(x, Wq, Wk, Wv, Wo, Wr, pe_raw, gmax, xb,
                                               WTqkv, WoTh, WoTl, WrT);
  pe_norm_kernel<<<4096 * 96 / 256, 256, 0, stream>>>(pe_raw, gmax, pe_bf);
  mfma_gemm<0, false><<<dim3(2560 / 128, BN * SEQ / 128), 256, 0, stream>>>(
      xb, nullptr, WTqkv, nullptr, nullptr, qb, kb, vtb, CDIM);
  mfma_gemm<1, false><<<dim3(HDK / 128, 4096 / 128), 256, 0, stream>>>(
      pe_bf, nullptr, WrT, nullptr, nullptr, rkb, nullptr, nullptr, 192);
  if (dosplit) {
    attn_mfma<true><<<dim3(SEQ / 64, 32), 256, 0, stream>>>(qb, kb, vtb, rkb, rwb, mask,
                                                            attnh, attnl, Opart, ml);
    combine_kernel<<<4096 * 384 / 256, 256, 0, stream>>>(Opart, ml, attnh, attnl);
  } else {
    attn_mfma<false><<<dim3(SEQ / 64, 16), 256, 0, stream>>>(qb, kb, vtb, rkb, rwb, mask,
                                                             attnh, attnl, nullptr, nullptr);
  }
  mfma_gemm<2, true><<<dim3(HDV / 128, BN * SEQ / 128), 256, 0, stream>>>(
      attnh, attnl, WoTh, WoTl, bo, out, nullptr, nullptr, CDIM);
}

// Round 5
// 356.082 us; speedup vs baseline: 14.6937x; 1.1662x over previous
//
#include <hip/hip_runtime.h>
#include <math.h>

#define SEQ 2048
#define CDIM 1536
#define HN 8
#define DVC 192
#define BN 2
#define NPOS 4095   // 2*SEQ-1
#define HDK 512     // H*DK
#define HDV 1536    // H*DV
#define PSTR 72     // Pbs LDS stride (halfs)

typedef __attribute__((ext_vector_type(8))) _Float16 hf8v;  // 8 f16 (4 VGPRs)
typedef __attribute__((ext_vector_type(4))) float f4v;      // MFMA C/D frag

static __device__ __forceinline__ f4v mfma16(hf8v a, hf8v b, f4v c) {
  return __builtin_amdgcn_mfma_f32_16x16x32_f16(a, b, c, 0, 0, 0);
}
static __device__ __forceinline__ void gl2lds16(const void* g, void* l) {
  __builtin_amdgcn_global_load_lds((const __attribute__((address_space(1))) unsigned int*)g,
                                   (__attribute__((address_space(3))) unsigned int*)l,
                                   16, 0, 0);
}

// ================= fused prep: pos-features + cast x + 5 weight transposes =================
#define PF_B   512
#define CAST_B 6144
#define TWQ_B  768
#define TWK_B  768
#define TWV_B  2304
#define TWO_B  2304
#define TWR_B  96
#define PREP_BLOCKS (PF_B + CAST_B + TWQ_B + TWK_B + TWV_B + TWO_B + TWR_B)

__device__ __forceinline__ void twc_tile(const float* __restrict__ W, _Float16* __restrict__ WT,
                                         int K, int N, int tile, float (*tls)[33], int tid) {
  int ntn = N >> 5;
  int nt = tile % ntn, kt = tile / ntn;
  int k0 = kt * 32, n0 = nt * 32;
  int tx = tid & 31, ty = tid >> 5;
#pragma unroll
  for (int p = 0; p < 4; p++) tls[ty + p * 8][tx] = W[(size_t)(k0 + ty + p * 8) * N + n0 + tx];
  __syncthreads();
#pragma unroll
  for (int p = 0; p < 4; p++) {
    int n = ty + p * 8;
    WT[(size_t)(n0 + n) * K + k0 + tx] = (_Float16)tls[tx][n];
  }
}

__global__ __launch_bounds__(256) void prep_kernel(
    const float* __restrict__ x, const float* __restrict__ Wq, const float* __restrict__ Wk,
    const float* __restrict__ Wv, const float* __restrict__ Wo, const float* __restrict__ Wr,
    float* __restrict__ pe_raw, unsigned* __restrict__ gmax, _Float16* __restrict__ xb,
    _Float16* __restrict__ WTqkv, _Float16* __restrict__ WoT, _Float16* __restrict__ WrT) {
  __shared__ float tls[32][33];
  int blk = blockIdx.x, tid = threadIdx.x;
  if (blk < PF_B) {
    int j = blk >> 4;
    int pos = (blk & 15) * 256 + tid;
    float prob = 0.0f;
    if (pos < NPOS) {
      float ap = fabsf((float)(pos - (SEQ - 1)));
      float hl = exp2f(3.0f + 8.0f * (float)j / 31.0f);
      float fe = exp2f(-ap / hl);
      float cw = exp2f((float)(j + 1)) - 1.0f;
      float fc = (cw > ap) ? 1.0f : 0.0f;
      float conc = 4.0f * (float)((j + 1) * (j + 1));
      float rate = (float)(j + 1) / 16.0f;
      float log_norm = lgammaf(conc) - conc * logf(rate);
      float log_un = (conc - 1.0f) * logf(ap) - rate * ap;
      prob = expf(log_un - log_norm) + 1e-8f;
      pe_raw[pos * 96 + j] = fe;
      pe_raw[pos * 96 + 32 + j] = fc;
      pe_raw[pos * 96 + 64 + j] = prob;
    }
    float m = prob;
#pragma unroll
    for (int off = 32; off > 0; off >>= 1) m = fmaxf(m, __shfl_down(m, off));
    __shared__ float red[4];
    if ((tid & 63) == 0) red[tid >> 6] = m;
    __syncthreads();
    if (tid == 0) {
      m = fmaxf(fmaxf(red[0], red[1]), fmaxf(red[2], red[3]));
      atomicMax(&gmax[j], __float_as_uint(m));
    }
  } else if (blk < PF_B + CAST_B) {
    int i = ((blk - PF_B) * 256 + tid) * 4;
    float4 v = *(const float4*)(x + i);
    _Float16 o[4] = {(_Float16)v.x, (_Float16)v.y, (_Float16)v.z, (_Float16)v.w};
    *(unsigned long long*)(xb + i) = *(const unsigned long long*)o;
  } else if (blk < PF_B + CAST_B + TWQ_B) {
    twc_tile(Wq, WTqkv + 0 * (size_t)CDIM, CDIM, HDK, blk - (PF_B + CAST_B), tls, tid);
  } else if (blk < PF_B + CAST_B + TWQ_B + TWK_B) {
    twc_tile(Wk, WTqkv + 512 * (size_t)CDIM, CDIM, HDK, blk - (PF_B + CAST_B + TWQ_B), tls, tid);
  } else if (blk < PF_B + CAST_B + TWQ_B + TWK_B + TWV_B) {
    twc_tile(Wv, WTqkv + 1024 * (size_t)CDIM, CDIM, HDV, blk - (PF_B + CAST_B + TWQ_B + TWK_B), tls, tid);
  } else if (blk < PF_B + CAST_B + TWQ_B + TWK_B + TWV_B + TWO_B) {
    twc_tile(Wo, WoT, CDIM, HDV, blk - (PF_B + CAST_B + TWQ_B + TWK_B + TWV_B), tls, tid);
  } else {
    twc_tile(Wr, WrT, 192, HDK, blk - (PF_B + CAST_B + TWQ_B + TWK_B + TWV_B + TWO_B), tls, tid);
  }
}

// ============ pe [4096][192] fp16: normalize gamma, apply sign-concat ============
__global__ __launch_bounds__(256) void pe_norm_kernel(const float* __restrict__ pe_raw,
                                                      const unsigned* __restrict__ gmax,
                                                      _Float16* __restrict__ pe_h) {
  int idx = blockIdx.x * 256 + threadIdx.x;  // over 4096*96
  int pos = idx / 96, f = idx - pos * 96;
  float val = 0.0f, sval = 0.0f;
  if (pos < NPOS) {
    val = pe_raw[pos * 96 + f];
    if (f >= 64) val *= 1.0f / __uint_as_float(gmax[f - 64]);
    float sgn = (pos > SEQ - 1) ? 1.0f : ((pos < SEQ - 1) ? -1.0f : 0.0f);
    sval = sgn * val;
  }
  pe_h[pos * 192 + f] = (_Float16)val;
  pe_h[pos * 192 + 96 + f] = (_Float16)sval;
}

// ================= fp16 MFMA GEMM, 128x128xBK32, XOR-swizzled LDS =================
// MODE 0 (QKV): c<512 -> qb*0.125 ; c<1024 -> kb[B,H,S,64] ; else vtb[B,H,192,S]
// MODE 1 (RK):  rkb[(h*4096+pos)*64+d]
// MODE 2 (OUT): fp32 out + bias
template <int MODE>
__global__ __launch_bounds__(256, 2) void mfma_gemm(
    const _Float16* __restrict__ A, const _Float16* __restrict__ B,
    const float* __restrict__ bias, void* __restrict__ out0, void* __restrict__ out1,
    void* __restrict__ out2, int K) {
  __shared__ __align__(16) _Float16 As[128 * 32];
  __shared__ __align__(16) _Float16 Bs[128 * 32];
  const int tid = threadIdx.x;
  const int lane = tid & 63, l15 = lane & 15, quad = lane >> 4;
  const int wv = tid >> 6;
  const int wm = (wv & 1) * 64, wn = (wv >> 1) * 64;
  const int row0 = blockIdx.y * 128, col0 = blockIdx.x * 128;
  f4v acc[4][4];
#pragma unroll
  for (int i = 0; i < 4; i++)
#pragma unroll
    for (int j = 0; j < 4; j++) acc[i][j] = (f4v)0.0f;

  for (int k0 = 0; k0 < K; k0 += 32) {
    __syncthreads();
#pragma unroll
    for (int p = 0; p < 2; p++) {
      int idx = tid + p * 256;
      int rr = idx >> 2, sc = idx & 3;
      int gc = (sc ^ ((rr >> 1) & 3)) << 3;
      gl2lds16(A + (size_t)(row0 + rr) * K + k0 + gc, As + idx * 8);
      gl2lds16(B + (size_t)(col0 + rr) * K + k0 + gc, Bs + idx * 8);
    }
    __syncthreads();
    hf8v af[4], bfr[4];
#pragma unroll
    for (int t = 0; t < 4; t++) {
      int lrA = wm + t * 16 + l15;
      int lrB = wn + t * 16 + l15;
      af[t] = *(const hf8v*)(As + lrA * 32 + ((quad ^ ((lrA >> 1) & 3)) << 3));
      bfr[t] = *(const hf8v*)(Bs + lrB * 32 + ((quad ^ ((lrB >> 1) & 3)) << 3));
    }
#pragma unroll
    for (int mt = 0; mt < 4; mt++)
#pragma unroll
      for (int nt = 0; nt < 4; nt++)
        acc[mt][nt] = mfma16(af[mt], bfr[nt], acc[mt][nt]);
  }
#pragma unroll
  for (int mt = 0; mt < 4; mt++)
#pragma unroll
    for (int reg = 0; reg < 4; reg++) {
      int r = row0 + wm + mt * 16 + quad * 4 + reg;
      int bb = r >> 11, ss = r & (SEQ - 1);
#pragma unroll
      for (int nt = 0; nt < 4; nt++) {
        int c = col0 + wn + nt * 16 + l15;
        float vv = acc[mt][nt][reg];
        if (MODE == 0) {
          if (c < 512) {
            ((_Float16*)out0)[(size_t)r * HDK + c] = (_Float16)(vv * 0.125f);
          } else if (c < 1024) {
            int cc = c - 512, h = cc >> 6, d = cc & 63;
            ((_Float16*)out1)[(((size_t)bb * HN + h) * SEQ + ss) * 64 + d] = (_Float16)vv;
          } else {
            int cc = c - 1024, h = cc / DVC, e = cc - h * DVC;
            ((_Float16*)out2)[(((size_t)bb * HN + h) * DVC + e) * SEQ + ss] = (_Float16)vv;
          }
        } else if (MODE == 1) {
          int h = c >> 6, d = c & 63;
          ((_Float16*)out0)[((size_t)h * 4096 + r) * 64 + d] = (_Float16)vv;
        } else {
          ((float*)out0)[(size_t)r * HDV + c] = vv + bias[c];
        }
      }
    }
}

// ================= flash MFMA attention: 128-q tile, 2 strips/wave =================
// grid (16, SPLITKV?32:16); 4 waves, wave w owns q-rows [i0+32w, i0+32w+32) as 2 strips of 16
template <bool SPLITKV>
__global__ __launch_bounds__(256, 2) void attn_mfma(
    const _Float16* __restrict__ qb, const _Float16* __restrict__ kb,
    const _Float16* __restrict__ vtb, const _Float16* __restrict__ rkb,
    const float* __restrict__ rwb, const int* __restrict__ mask,
    _Float16* __restrict__ attn_out, float* __restrict__ Opart, float* __restrict__ ml) {
  __shared__ __align__(16) _Float16 Vts[192 * 64];   // 24576 B
  __shared__ __align__(16) _Float16 RKU[192 * 64];   // RKs; Pbs[128][PSTR] aliases (18432 B)
  __shared__ __align__(16) _Float16 Kts[64 * 64];    // 8192 B
  __shared__ float mb[64];
  _Float16* RKs = RKU;
  _Float16* Pbs = RKU;

  const int i0 = blockIdx.x * 128;
  const int by = blockIdx.y;
  const int bh = SPLITKV ? (by & 15) : by;
  const int half = SPLITKV ? (by >> 4) : 0;
  const int b = bh >> 3, h = bh & 7;
  const int tid = threadIdx.x;
  const int wv = tid >> 6, lane = tid & 63;
  const int l15 = lane & 15, quad = lane >> 4;

  // Q A-fragments, 2 strips (held in VGPRs across all key tiles)
  hf8v qf[2][2], qbf[2][2];
#pragma unroll
  for (int s = 0; s < 2; s++) {
    int qrow = i0 + wv * 32 + s * 16 + l15;
    const _Float16* qp = qb + (size_t)(b * SEQ + qrow) * HDK + h * 64;
#pragma unroll
    for (int kc = 0; kc < 2; kc++) {
      hf8v qv = *(const hf8v*)(qp + kc * 32 + quad * 8);
      qf[s][kc] = qv;
      hf8v t;
#pragma unroll
      for (int j = 0; j < 8; j++)
        t[j] = (_Float16)((float)qv[j] + rwb[h * 64 + kc * 32 + quad * 8 + j]);
      qbf[s][kc] = t;
    }
  }

  f4v Of[2][12];
#pragma unroll
  for (int s = 0; s < 2; s++)
#pragma unroll
    for (int se = 0; se < 12; se++) Of[s][se] = (f4v)0.0f;
  float m_i[2][4] = {{-INFINITY, -INFINITY, -INFINITY, -INFINITY},
                     {-INFINITY, -INFINITY, -INFINITY, -INFINITY}};
  float l_i[2][4] = {{0.f, 0.f, 0.f, 0.f}, {0.f, 0.f, 0.f, 0.f}};

  const int j0beg = SPLITKV ? half * (SEQ / 2) : 0;
  const int j0end = SPLITKV ? j0beg + SEQ / 2 : SEQ;

  for (int j0 = j0beg; j0 < j0end; j0 += 64) {
    __syncthreads();  // prior-tile readers done before staging overwrites
    {
      const int U0 = j0 - i0 + 1920;  // 192-row window base, in [0, 3904]
#pragma unroll
      for (int r = 0; r < 2; r++) {
        int idx = tid + r * 256, row = idx >> 3, sc = idx & 7;
        gl2lds16(kb + ((size_t)bh * SEQ + j0 + row) * 64 + ((sc ^ (row & 7)) << 3), Kts + idx * 8);
      }
#pragma unroll
      for (int r = 0; r < 6; r++) {
        int idx = tid + r * 256, row = idx >> 3, sc = idx & 7;
        gl2lds16(vtb + ((size_t)bh * DVC + row) * SEQ + j0 + ((sc ^ (row & 7)) << 3), Vts + idx * 8);
      }
#pragma unroll
      for (int r = 0; r < 6; r++) {
        int idx = tid + r * 256, row = idx >> 3, sc = idx & 7;
        gl2lds16(rkb + ((size_t)h * 4096 + U0 + row) * 64 + ((sc ^ (row & 7)) << 3), RKs + idx * 8);
      }
      if (tid < 64) mb[tid] = mask[b * SEQ + j0 + tid] ? 0.f : -1e9f;
    }
    __syncthreads();  // staging (vmcnt) drained

    // rel logits for BOTH strips first (RKs consumed before Pbs aliases it)
    f4v Rf[2][5];
#pragma unroll
    for (int s = 0; s < 2; s++) {
      const int tb = 112 - 32 * wv - 16 * s;
#pragma unroll
      for (int u = 0; u < 5; u++) {
        Rf[s][u] = (f4v)0.0f;
#pragma unroll
        for (int kc = 0; kc < 2; kc++) {
          int row = tb + u * 16 + l15;
          hf8v rf = *(const hf8v*)(RKs + row * 64 + ((((kc << 2) | quad) ^ (row & 7)) << 3));
          Rf[s][u] = mfma16(qbf[s][kc], rf, Rf[s][u]);
        }
      }
    }
    __syncthreads();  // all waves done reading RKs; P may now alias

    float mv[4];
#pragma unroll
    for (int st = 0; st < 4; st++) mv[st] = mb[st * 16 + l15];

#pragma unroll
    for (int s = 0; s < 2; s++) {
      // content logits
      f4v Sf[4];
#pragma unroll
      for (int st = 0; st < 4; st++) {
        Sf[st] = (f4v)0.0f;
#pragma unroll
        for (int kc = 0; kc < 2; kc++) {
          int row = st * 16 + l15;
          hf8v kf = *(const hf8v*)(Kts + row * 64 + ((((kc << 2) | quad) ^ (row & 7)) << 3));
          Sf[st] = mfma16(qf[s][kc], kf, Sf[st]);
        }
      }
      // band extraction via bpermute: S[r][c] += R[r][c-r+15]
#pragma unroll
      for (int reg = 0; reg < 4; reg++) {
        int delta = l15 - (quad << 2) - reg + 15;  // [0,30]
        int srcl = (quad << 4) | (delta & 15);
        float sh0 = __shfl(Rf[s][0][reg], srcl, 64);
        float sh1 = __shfl(Rf[s][1][reg], srcl, 64);
        float sh2 = __shfl(Rf[s][2][reg], srcl, 64);
        float sh3 = __shfl(Rf[s][3][reg], srcl, 64);
        float sh4 = __shfl(Rf[s][4][reg], srcl, 64);
        bool hib = delta >= 16;
        Sf[0][reg] += (hib ? sh1 : sh0) + mv[0];
        Sf[1][reg] += (hib ? sh2 : sh1) + mv[1];
        Sf[2][reg] += (hib ? sh3 : sh2) + mv[2];
        Sf[3][reg] += (hib ? sh4 : sh3) + mv[3];
      }
      // online softmax
#pragma unroll
      for (int reg = 0; reg < 4; reg++) {
        float t = fmaxf(fmaxf(Sf[0][reg], Sf[1][reg]), fmaxf(Sf[2][reg], Sf[3][reg]));
        t = fmaxf(t, __shfl_xor(t, 1));
        t = fmaxf(t, __shfl_xor(t, 2));
        t = fmaxf(t, __shfl_xor(t, 4));
        t = fmaxf(t, __shfl_xor(t, 8));
        float mn = fmaxf(m_i[s][reg], t);
        float alpha = __expf(m_i[s][reg] - mn);
        m_i[s][reg] = mn;
        if (__ballot(alpha != 1.0f)) {
          l_i[s][reg] *= alpha;
#pragma unroll
          for (int se = 0; se < 12; se++) Of[s][se][reg] *= alpha;
        }
        float rs = 0.f;
#pragma unroll
        for (int st = 0; st < 4; st++) {
          float p = __expf(Sf[st][reg] - mn);
          rs += p;
          Pbs[(wv * 32 + s * 16 + quad * 4 + reg) * PSTR + st * 16 + l15] = (_Float16)p;
        }
        rs += __shfl_xor(rs, 1);
        rs += __shfl_xor(rs, 2);
        rs += __shfl_xor(rs, 4);
        rs += __shfl_xor(rs, 8);
        l_i[s][reg] += rs;
      }
    }

    // PV: V B-fragments shared by both strips
    hf8v pa[2][2];
#pragma unroll
    for (int s = 0; s < 2; s++)
#pragma unroll
      for (int kc = 0; kc < 2; kc++)
        pa[s][kc] = *(const hf8v*)(Pbs + (wv * 32 + s * 16 + l15) * PSTR + kc * 32 + quad * 8);
#pragma unroll
    for (int se = 0; se < 12; se++) {
#pragma unroll
      for (int kc = 0; kc < 2; kc++) {
        int row = se * 16 + l15;
        hf8v vf = *(const hf8v*)(Vts + row * 64 + ((((kc << 2) | quad) ^ (row & 7)) << 3));
        Of[0][se] = mfma16(pa[0][kc], vf, Of[0][se]);
        Of[1][se] = mfma16(pa[1][kc], vf, Of[1][se]);
      }
    }
  }

#pragma unroll
  for (int s = 0; s < 2; s++)
#pragma unroll
    for (int reg = 0; reg < 4; reg++) {
      int row = i0 + wv * 32 + s * 16 + quad * 4 + reg;
      int rg = b * SEQ + row;
      if constexpr (SPLITKV) {
        float* Op = Opart + ((size_t)(half * 4096 + rg)) * HDV + h * DVC;
#pragma unroll
        for (int se = 0; se < 12; se++) Op[se * 16 + l15] = Of[s][se][reg];
        if (l15 == 0) {
          size_t mlb = (((size_t)half * 4096 + rg) * HN + h) * 2;
          ml[mlb] = m_i[s][reg];
          ml[mlb + 1] = l_i[s][reg];
        }
      } else {
        float inv = 1.0f / l_i[s][reg];
        size_t base = (size_t)rg * HDV + h * DVC;
#pragma unroll
        for (int se = 0; se < 12; se++)
          attn_out[base + se * 16 + l15] = (_Float16)(Of[s][se][reg] * inv);
      }
    }
}

// ================= combine the two KV halves =================
__global__ __launch_bounds__(256) void combine_kernel(const float* __restrict__ Opart,
                                                      const float* __restrict__ ml,
                                                      _Float16* __restrict__ attn_out) {
  int i4 = blockIdx.x * 256 + threadIdx.x;  // over 4096*384
  int rg = i4 / 384, c4 = (i4 - rg * 384) * 4;
  int h = c4 / DVC;
  size_t mlb0 = ((size_t)rg * HN + h) * 2;
  size_t mlb1 = (((size_t)4096 + rg) * HN + h) * 2;
  float m0 = ml[mlb0], l0 = ml[mlb0 + 1];
  float m1 = ml[mlb1], l1 = ml[mlb1 + 1];
  float M = fmaxf(m0, m1);
  float w0 = __expf(m0 - M), w1 = __expf(m1 - M);
  float inv = 1.0f / (l0 * w0 + l1 * w1);
  float4 O0 = *(const float4*)(Opart + (size_t)rg * HDV + c4);
  float4 O1 = *(const float4*)(Opart + ((size_t)4096 + rg) * HDV + c4);
  _Float16 o[4] = {(_Float16)((O0.x * w0 + O1.x * w1) * inv),
                   (_Float16)((O0.y * w0 + O1.y * w1) * inv),
                   (_Float16)((O0.z * w0 + O1.z * w1) * inv),
                   (_Float16)((O0.w * w0 + O1.w * w1) * inv)};
  *(unsigned long long*)(attn_out + (size_t)rg * HDV + c4) = *(const unsigned long long*)o;
}

extern "C" void kernel_launch(void* const* d_in, const int* in_sizes, int n_in,
                              void* d_out, int out_size, void* d_ws, size_t ws_size,
                              hipStream_t stream) {
  const float* x    = (const float*)d_in[0];
  const int*   mask = (const int*)d_in[1];
  const float* Wq   = (const float*)d_in[2];
  const float* Wk   = (const float*)d_in[3];
  const float* Wv   = (const float*)d_in[4];
  const float* Wr   = (const float*)d_in[5];
  const float* rwb  = (const float*)d_in[6];
  const float* Wo   = (const float*)d_in[7];
  const float* bo   = (const float*)d_in[8];
  float* out = (float*)d_out;

  char* wsb = (char*)d_ws;
  size_t o = 0;
  auto al = [](size_t v) { return (v + 255) & ~(size_t)255; };
#define CARVE(ptr_t, name, bytes) ptr_t name = (ptr_t)(wsb + o); o = al(o + (bytes));
  CARVE(float*, pe_raw, (size_t)4096 * 96 * 4)
  CARVE(unsigned*, gmax, 128)
  CARVE(_Float16*, pe_h, (size_t)4096 * 192 * 2)
  CARVE(_Float16*, WrT, (size_t)HDK * 192 * 2)
  CARVE(_Float16*, xb, (size_t)BN * SEQ * CDIM * 2)
  CARVE(_Float16*, WTqkv, (size_t)2560 * CDIM * 2)
  CARVE(_Float16*, WoT, (size_t)HDV * CDIM * 2)
  CARVE(_Float16*, qb, (size_t)BN * SEQ * HDK * 2)
  CARVE(_Float16*, kb, (size_t)BN * SEQ * HDK * 2)
  CARVE(_Float16*, vtb, (size_t)BN * SEQ * HDV * 2)
  CARVE(_Float16*, rkb, (size_t)HN * 4096 * 64 * 2)
  _Float16* attnh = xb;  // xb dead after QKV gemm -> safe alias
  CARVE(float*, Opart, (size_t)2 * 4096 * HDV * 4)
  CARVE(float*, ml, (size_t)2 * 4096 * HN * 2 * 4)
  bool dosplit = (o <= ws_size);

  hipMemsetAsync(gmax, 0, 32 * sizeof(unsigned), stream);
  prep_kernel<<<PREP_BLOCKS, 256, 0, stream>>>(x, Wq, Wk, Wv, Wo, Wr, pe_raw, gmax, xb,
                                               WTqkv, WoT, WrT);
  pe_norm_kernel<<<4096 * 96 / 256, 256, 0, stream>>>(pe_raw, gmax, pe_h);
  mfma_gemm<0><<<dim3(2560 / 128, BN * SEQ / 128), 256, 0, stream>>>(
      xb, WTqkv, nullptr, qb, kb, vtb, CDIM);
  mfma_gemm<1><<<dim3(HDK / 128, 4096 / 128), 256, 0, stream>>>(
      pe_h, WrT, nullptr, rkb, nullptr, nullptr, 192);
  if (dosplit) {
    attn_mfma<true><<<dim3(SEQ / 128, 32), 256, 0, stream>>>(qb, kb, vtb, rkb, rwb, mask,
                                                             attnh, Opart, ml);
    combine_kernel<<<4096 * 384 / 256, 256, 0, stream>>>(Opart, ml, attnh);
  } else {
    attn_mfma<false><<<dim3(SEQ / 128, 16), 256, 0, stream>>>(qb, kb, vtb, rkb, rwb, mask,
                                                              attnh, nullptr, nullptr);
  }
  mfma_gemm<2><<<dim3(HDV / 128, BN * SEQ / 128), 256, 0, stream>>>(
      attnh, WoT, bo, out, nullptr, nullptr, CDIM);
}